// Round 6
// baseline (134.754 us; speedup 1.0000x reference)
//
#include <hip/hip_runtime.h>
#include <hip/hip_bf16.h>

#define NE 1024       // N_EMBD
#define NH 16         // N_HEAD
#define HD 64         // HEAD_SIZE
#define TSEQ 2048
#define BATCH 2

typedef __attribute__((ext_vector_type(8))) short bf16x8;
typedef __attribute__((ext_vector_type(4))) float f32x4;
typedef __attribute__((ext_vector_type(4))) unsigned int u32x4;
typedef unsigned short u16;
typedef unsigned int u32;

__device__ inline u16 f2bf(float f) {
    __hip_bfloat16 h = __float2bfloat16(f);
    return *reinterpret_cast<u16*>(&h);
}

__device__ inline float bf2f(u32 bits) {
    u32 v = bits << 16;
    return __builtin_bit_cast(float, v);
}

__device__ inline u32 cvt_pk_bf16(float lo, float hi) {
    u32 r;
    asm("v_cvt_pk_bf16_f32 %0, %1, %2" : "=v"(r) : "v"(lo), "v"(hi));
    return r;
}

#define GLD16(gptr, lptr)                                                        \
    __builtin_amdgcn_global_load_lds(                                            \
        (const __attribute__((address_space(1))) void*)(gptr),                   \
        (__attribute__((address_space(3))) void*)(lptr), 16, 0, 0)

// ---------- elementwise f32 -> bf16 ----------
__global__ void k_f32_to_bf16(const float* __restrict__ in, u16* __restrict__ out, int n4) {
    int i = blockIdx.x * blockDim.x + threadIdx.x;
    int stride = gridDim.x * blockDim.x;
    for (; i < n4; i += stride) {
        float4 v = reinterpret_cast<const float4*>(in)[i];
        ushort4 o;
        o.x = f2bf(v.x); o.y = f2bf(v.y); o.z = f2bf(v.z); o.w = f2bf(v.w);
        reinterpret_cast<ushort4*>(out)[i] = o;
    }
}

// ---------- transpose + convert: in [K][N] f32 -> out [N][K] bf16 ----------
__global__ void k_transpose_bf16(const float* __restrict__ in, u16* __restrict__ out,
                                 int K, int N) {
    __shared__ float tile[32][33];
    int bn = blockIdx.x * 32;
    int bk = blockIdx.y * 32;
    int tx = threadIdx.x, ty = threadIdx.y;
#pragma unroll
    for (int i = 0; i < 32; i += 8)
        tile[ty + i][tx] = in[(size_t)(bk + ty + i) * N + bn + tx];
    __syncthreads();
#pragma unroll
    for (int i = 0; i < 32; i += 8)
        out[(size_t)(bn + ty + i) * K + bk + tx] = f2bf(tile[tx][ty + i]);
}

// ---------- GEMM: C[M,N] = A[M,K] * Bt[N,K]^T + bias ----------
// MODE 0: scatter q/k -> [B,H,T,D] bf16, v -> [B,H,D,T] bf16 (transposed)
// MODE 1: plain f32 out
template <int MODE>
__global__ __launch_bounds__(256, 2) void k_gemm_bt(
    const u16* __restrict__ A, const u16* __restrict__ Bt,
    const float* __restrict__ bias, void* __restrict__ outp,
    int M, int N, int K) {
    __shared__ __align__(16) u16 As[128 * 32];
    __shared__ __align__(16) u16 Bs[128 * 32];
    const int l = threadIdx.x & 63;
    const int w = threadIdx.x >> 6;
    const int m0 = blockIdx.x * 128;
    const int n0 = blockIdx.y * 128;
    const int wr = w >> 1, wc = w & 1;

    f32x4 acc[4][4] = {};
    const int nkt = K >> 5;
    for (int kt = 0; kt < nkt; ++kt) {
        __syncthreads();
#pragma unroll
        for (int i = 0; i < 2; ++i) {
            int c = w * 2 + i;
            const u16* gA = A + (size_t)(m0 + c * 16 + (l >> 2)) * K + (kt << 5) + (l & 3) * 8;
            const u16* gB = Bt + (size_t)(n0 + c * 16 + (l >> 2)) * K + (kt << 5) + (l & 3) * 8;
            GLD16(gA, As + c * 512);
            GLD16(gB, Bs + c * 512);
        }
        __syncthreads();
        bf16x8 af[4], bfr[4];
#pragma unroll
        for (int mi = 0; mi < 4; ++mi)
            af[mi] = *reinterpret_cast<const bf16x8*>(As + (wr * 64 + mi * 16 + (l & 15)) * 32 + (l >> 4) * 8);
#pragma unroll
        for (int ni = 0; ni < 4; ++ni)
            bfr[ni] = *reinterpret_cast<const bf16x8*>(Bs + (wc * 64 + ni * 16 + (l & 15)) * 32 + (l >> 4) * 8);
#pragma unroll
        for (int mi = 0; mi < 4; ++mi)
#pragma unroll
            for (int ni = 0; ni < 4; ++ni)
                acc[mi][ni] = __builtin_amdgcn_mfma_f32_16x16x32_bf16(af[mi], bfr[ni], acc[mi][ni], 0, 0, 0);
    }

    if (MODE == 1) {
        float* C = (float*)outp;
#pragma unroll
        for (int mi = 0; mi < 4; ++mi)
#pragma unroll
            for (int ni = 0; ni < 4; ++ni) {
                int n = n0 + wc * 64 + ni * 16 + (l & 15);
                float bv = bias[n];
#pragma unroll
                for (int r = 0; r < 4; ++r) {
                    int m = m0 + wr * 64 + mi * 16 + (l >> 4) * 4 + r;
                    C[(size_t)m * N + n] = acc[mi][ni][r] + bv;
                }
            }
    } else {
        u16* qkv = (u16*)outp;
        const size_t headsz = (size_t)BATCH * NH * TSEQ * HD;
#pragma unroll
        for (int mi = 0; mi < 4; ++mi)
#pragma unroll
            for (int ni = 0; ni < 4; ++ni) {
                int n = n0 + wc * 64 + ni * 16 + (l & 15);
                float bv = bias[n];
                int which = n >> 10;
                int c = n & 1023;
                int h = c >> 6, d = c & 63;
#pragma unroll
                for (int r = 0; r < 4; ++r) {
                    int m = m0 + wr * 64 + mi * 16 + (l >> 4) * 4 + r;
                    int b = m >> 11, t = m & 2047;
                    float v = acc[mi][ni][r] + bv;
                    size_t dst;
                    if (which == 2)  // V stored transposed: [B,H,D,T]
                        dst = 2 * headsz + ((size_t)(b * NH + h) * HD + d) * TSEQ + t;
                    else
                        dst = (size_t)which * headsz + ((size_t)(b * NH + h) * TSEQ + t) * HD + d;
                    qkv[dst] = f2bf(v);
                }
            }
    }
}

// ---------- causal flash attention, wave-split K, barrier-free main loop ----------
// grid: 1024 blocks (32 q-tiles x 32 bh), 4 waves, 64KB LDS (2 blocks/CU).
// Block = 64 q-rows. Wave w processes kt = w, w+4, ... with a PRIVATE 16KB
// LDS region (K 8KB + V^T 8KB): global_load_lds + wave-local vmcnt wait,
// no __syncthreads in the loop. Swapped MFMA (S^T / O^T) keeps softmax
// lane-local; P redistributed in-register via shfl. Final 4-way merge of
// online-softmax partials (bf16 o, f32 m/l) through LDS.
__global__ __launch_bounds__(256, 2) void k_attn(
    const u16* __restrict__ qb, const u16* __restrict__ kb, const u16* __restrict__ vtb,
    u16* __restrict__ attn_out) {
    __shared__ __align__(16) u16 stage[4][8192];  // 64KB; reused for the merge
    const int l = threadIdx.x & 63;
    const int w = threadIdx.x >> 6;
    const int g = l >> 4, l15 = l & 15;

    const int bid = blockIdx.x;
    const int t = 31 - (bid >> 5);   // heavy q-tiles dispatched first
    const int bh = bid & 31;
    const int q0 = t * 64;
    const int b = bh >> 4, h = bh & 15;
    const size_t base = (size_t)bh * TSEQ * HD;
    const u16* Q = qb + base;
    const u16* Kg = kb + base;
    const u16* Vg = vtb + base;  // [64 d][2048 t]

    const int lrow8 = l >> 3;
    const int lchunk = (l & 7) ^ lrow8;  // inverse-swizzled source chunk

    u16* myK = &stage[w][0];
    u16* myV = &stage[w][4096];

    // Q fragments for all 4 16-row n-blocks: qa[qn][ks]
    bf16x8 qa[4][2];
#pragma unroll
    for (int qn = 0; qn < 4; ++qn)
#pragma unroll
        for (int ks = 0; ks < 2; ++ks)
            qa[qn][ks] = *reinterpret_cast<const bf16x8*>(
                Q + (size_t)(q0 + qn * 16 + l15) * HD + ks * 32 + g * 8);
    // drain Q loads so vmcnt counting in the loop is exact
    asm volatile("s_waitcnt vmcnt(0)" ::: "memory");

    float m[4], lsum[4];
    f32x4 o[4][4] = {};  // [qn][nf]
#pragma unroll
    for (int r = 0; r < 4; ++r) { m[r] = -1e30f; lsum[r] = 0.f; }

    const int ntiles = t + 1;
    const float SC = 0.125f * 1.44269504f;  // log2(e)/sqrt(64)
    const float THRU = 44.3614f;            // 8/SC (defer-max threshold, unscaled)

    const int srcA = ((2 * g) & 3) * 16 + l15;
    const int srcB = ((2 * g + 1) & 3) * 16 + l15;
    const bool losel = (g < 2);

    for (int kt = w; kt < ntiles; kt += 4) {
        __builtin_amdgcn_sched_barrier(0);
        const u16* Kt = Kg + (size_t)kt * 64 * HD;
#pragma unroll
        for (int c = 0; c < 8; ++c)
            GLD16(Kt + (size_t)(c * 8 + lrow8) * HD + lchunk * 8, myK + c * 512);
#pragma unroll
        for (int c = 0; c < 8; ++c)
            GLD16(Vg + (size_t)(c * 8 + lrow8) * TSEQ + kt * 64 + lchunk * 8, myV + c * 512);
        asm volatile("s_waitcnt vmcnt(0)" ::: "memory");
        __builtin_amdgcn_sched_barrier(0);

        // S^T = mfma(A=K-frag, B=Q-frag): s[f][qn][r] = S[q=q0+qn*16+l15][k=kt*64+f*16+g*4+r]
        f32x4 s[4][4] = {};
        __builtin_amdgcn_s_setprio(1);
#pragma unroll
        for (int ks = 0; ks < 2; ++ks)
#pragma unroll
            for (int f = 0; f < 4; ++f) {
                bf16x8 bk = *reinterpret_cast<const bf16x8*>(
                    myK + (f * 16 + l15) * 64 + (((ks * 4 + g) ^ (l15 & 7)) * 8));
#pragma unroll
                for (int qn = 0; qn < 4; ++qn)
                    s[f][qn] = __builtin_amdgcn_mfma_f32_16x16x32_bf16(bk, qa[qn][ks], s[f][qn], 0, 0, 0);
            }
        __builtin_amdgcn_s_setprio(0);

        // causal mask (only the wave that owns the diagonal tile)
        if (kt == ntiles - 1) {
#pragma unroll
            for (int f = 0; f < 4; ++f)
#pragma unroll
                for (int qn = 0; qn < 4; ++qn)
#pragma unroll
                    for (int r = 0; r < 4; ++r) {
                        int kg = (kt << 6) + f * 16 + g * 4 + r;
                        int qg = q0 + qn * 16 + l15;
                        if (kg > qg) s[f][qn][r] = -1e30f;
                    }
        }

        // per-qn lane-local online softmax + bf16 pack
        u32 pk0[4][4], pk1[4][4];  // [qn][f]
#pragma unroll
        for (int qn = 0; qn < 4; ++qn) {
            float rmax = -1e30f;
#pragma unroll
            for (int f = 0; f < 4; ++f)
                rmax = fmaxf(rmax, fmaxf(fmaxf(s[f][qn][0], s[f][qn][1]),
                                         fmaxf(s[f][qn][2], s[f][qn][3])));
            rmax = fmaxf(rmax, __shfl_xor(rmax, 16));
            rmax = fmaxf(rmax, __shfl_xor(rmax, 32));

            if (__any(rmax - m[qn] > THRU)) {
                float mnew = fmaxf(m[qn], rmax);
                float alpha = exp2f((m[qn] - mnew) * SC);
                m[qn] = mnew;
                lsum[qn] *= alpha;
#pragma unroll
                for (int nf = 0; nf < 4; ++nf)
#pragma unroll
                    for (int r = 0; r < 4; ++r)
                        o[qn][nf][r] *= alpha;
            }
            const float mc = m[qn] * SC;
            float rsum = 0.f;
            float pe[4][4];
#pragma unroll
            for (int f = 0; f < 4; ++f)
#pragma unroll
                for (int r = 0; r < 4; ++r) {
                    float v = exp2f(__builtin_fmaf(s[f][qn][r], SC, -mc));
                    pe[f][r] = v;
                    rsum += v;
                }
            rsum += __shfl_xor(rsum, 16);
            rsum += __shfl_xor(rsum, 32);
            lsum[qn] += rsum;
#pragma unroll
            for (int f = 0; f < 4; ++f) {
                pk0[qn][f] = cvt_pk_bf16(pe[f][0], pe[f][1]);
                pk1[qn][f] = cvt_pk_bf16(pe[f][2], pe[f][3]);
            }
        }

        // O^T += mfma(A=V^T-frag, B=P-frag)
        __builtin_amdgcn_s_setprio(1);
#pragma unroll
        for (int ks = 0; ks < 2; ++ks) {
            bf16x8 pb[4];
#pragma unroll
            for (int qn = 0; qn < 4; ++qn) {
                u32 t00 = (u32)__shfl((int)pk0[qn][2 * ks], srcA);
                u32 t01 = (u32)__shfl((int)pk0[qn][2 * ks + 1], srcA);
                u32 t10 = (u32)__shfl((int)pk1[qn][2 * ks], srcA);
                u32 t11 = (u32)__shfl((int)pk1[qn][2 * ks + 1], srcA);
                u32 t20 = (u32)__shfl((int)pk0[qn][2 * ks], srcB);
                u32 t21 = (u32)__shfl((int)pk0[qn][2 * ks + 1], srcB);
                u32 t30 = (u32)__shfl((int)pk1[qn][2 * ks], srcB);
                u32 t31 = (u32)__shfl((int)pk1[qn][2 * ks + 1], srcB);
                u32x4 bb;
                bb.x = losel ? t00 : t01;
                bb.y = losel ? t10 : t11;
                bb.z = losel ? t20 : t21;
                bb.w = losel ? t30 : t31;
                pb[qn] = __builtin_bit_cast(bf16x8, bb);
            }
#pragma unroll
            for (int nf = 0; nf < 4; ++nf) {
                bf16x8 bv = *reinterpret_cast<const bf16x8*>(
                    myV + (nf * 16 + l15) * 64 + (((ks * 4 + g) ^ (l15 & 7)) * 8));
#pragma unroll
                for (int qn = 0; qn < 4; ++qn)
                    o[qn][nf] = __builtin_amdgcn_mfma_f32_16x16x32_bf16(bv, pb[qn], o[qn][nf], 0, 0, 0);
            }
        }
        __builtin_amdgcn_s_setprio(0);
    }

    // ---- merge the 4 waves' online-softmax partials ----
    __syncthreads();
    u16* om = &stage[0][0];                            // [4][64][66] bf16 (padded)
    float* ml = (float*)(&stage[0][0] + 16896);        // [4][2][64] f32

#pragma unroll
    for (int qn = 0; qn < 4; ++qn) {
        int q = qn * 16 + l15;
        if (g == 0) {
            ml[(w * 2 + 0) * 64 + q] = m[qn];
            ml[(w * 2 + 1) * 64 + q] = lsum[qn];
        }
#pragma unroll
        for (int nf = 0; nf < 4; ++nf) {
            u32* dst = (u32*)&om[(w * 64 + q) * 66 + nf * 16 + g * 4];
            dst[0] = cvt_pk_bf16(o[qn][nf][0], o[qn][nf][1]);
            dst[1] = cvt_pk_bf16(o[qn][nf][2], o[qn][nf][3]);
        }
    }
    __syncthreads();

    // wave w merges + stores d-block [w*16, w*16+16)
#pragma unroll
    for (int qn = 0; qn < 4; ++qn) {
        int q = qn * 16 + l15;
        float mw[4], lw[4];
#pragma unroll
        for (int ws = 0; ws < 4; ++ws) {
            mw[ws] = ml[(ws * 2 + 0) * 64 + q];
            lw[ws] = ml[(ws * 2 + 1) * 64 + q];
        }
        float M = fmaxf(fmaxf(mw[0], mw[1]), fmaxf(mw[2], mw[3]));
        float L = 0.f, a0 = 0.f, a1 = 0.f, a2 = 0.f, a3 = 0.f;
#pragma unroll
        for (int ws = 0; ws < 4; ++ws) {
            float sc = exp2f((mw[ws] - M) * SC);
            L += lw[ws] * sc;
            const u32* src = (const u32*)&om[(ws * 64 + q) * 66 + w * 16 + g * 4];
            u32 x = src[0], y = src[1];
            a0 += bf2f(x & 0xffffu) * sc;
            a1 += bf2f(x >> 16) * sc;
            a2 += bf2f(y & 0xffffu) * sc;
            a3 += bf2f(y >> 16) * sc;
        }
        float inv = 1.f / L;
        u32 p01 = cvt_pk_bf16(a0 * inv, a1 * inv);
        u32 p23 = cvt_pk_bf16(a2 * inv, a3 * inv);
        u16* orow = attn_out + (size_t)(b * TSEQ + q0 + q) * NE + h * HD + w * 16 + g * 4;
        *reinterpret_cast<u32*>(orow) = p01;
        *reinterpret_cast<u32*>(orow + 2) = p23;
    }
}

extern "C" void kernel_launch(void* const* d_in, const int* in_sizes, int n_in,
                              void* d_out, int out_size, void* d_ws, size_t ws_size,
                              hipStream_t stream) {
    const float* x = (const float*)d_in[0];
    const float* W_attn = (const float*)d_in[1];
    const float* b_attn = (const float*)d_in[2];
    const float* W_proj = (const float*)d_in[3];
    const float* b_proj = (const float*)d_in[4];
    float* out = (float*)d_out;

    char* ws = (char*)d_ws;
    u16* xb   = (u16*)(ws);                          // [4096,1024] bf16, 8MB
    u16* WaT  = (u16*)(ws + 8u * 1024 * 1024);       // [3072,1024] bf16, 6MB
    u16* WpT  = (u16*)(ws + 14u * 1024 * 1024);      // [1024,1024] bf16, 2MB
    u16* qkvb = (u16*)(ws + 16u * 1024 * 1024);      // q,k [B,H,T,D], v [B,H,D,T], 24MB
    u16* attn = (u16*)(ws + 40u * 1024 * 1024);      // [4096,1024] bf16, 8MB

    const int M = BATCH * TSEQ;  // 4096

    k_f32_to_bf16<<<2048, 256, 0, stream>>>(x, xb, (M * NE) / 4);
    k_transpose_bf16<<<dim3(3 * NE / 32, NE / 32), dim3(32, 8), 0, stream>>>(W_attn, WaT, NE, 3 * NE);
    k_transpose_bf16<<<dim3(NE / 32, NE / 32), dim3(32, 8), 0, stream>>>(W_proj, WpT, NE, NE);

    k_gemm_bt<0><<<dim3(M / 128, (3 * NE) / 128), 256, 0, stream>>>(xb, WaT, b_attn, qkvb, M, 3 * NE, NE);

    const size_t headsz = (size_t)BATCH * NH * TSEQ * HD;  // 4M elems
    k_attn<<<dim3(32 * 32), 256, 0, stream>>>(qkvb, qkvb + headsz, qkvb + 2 * headsz, attn);

    k_gemm_bt<1><<<dim3(M / 128, NE / 128), 256, 0, stream>>>(attn, WpT, b_proj, out, M, NE, NE);
}

// Round 7
// 130.153 us; speedup vs baseline: 1.0353x; 1.0353x over previous
//
#include <hip/hip_runtime.h>
#include <hip/hip_bf16.h>

#define NE 1024       // N_EMBD
#define NH 16         // N_HEAD
#define HD 64         // HEAD_SIZE
#define TSEQ 2048
#define BATCH 2
#define MB (1024u * 1024u)

typedef __attribute__((ext_vector_type(8))) short bf16x8;
typedef __attribute__((ext_vector_type(4))) float f32x4;
typedef __attribute__((ext_vector_type(4))) unsigned int u32x4;
typedef unsigned short u16;
typedef unsigned int u32;

__device__ inline u16 f2bf(float f) {
    __hip_bfloat16 h = __float2bfloat16(f);
    return *reinterpret_cast<u16*>(&h);
}

__device__ inline float bf2f(u32 bits) {
    u32 v = bits << 16;
    return __builtin_bit_cast(float, v);
}

__device__ inline u32 cvt_pk_bf16(float lo, float hi) {
    u32 r;
    asm("v_cvt_pk_bf16_f32 %0, %1, %2" : "=v"(r) : "v"(lo), "v"(hi));
    return r;
}

#define GLD16(gptr, lptr)                                                        \
    __builtin_amdgcn_global_load_lds(                                            \
        (const __attribute__((address_space(1))) void*)(gptr),                   \
        (__attribute__((address_space(3))) void*)(lptr), 16, 0, 0)

// ---------- elementwise f32 -> bf16 ----------
__global__ void k_f32_to_bf16(const float* __restrict__ in, u16* __restrict__ out, int n4) {
    int i = blockIdx.x * blockDim.x + threadIdx.x;
    int stride = gridDim.x * blockDim.x;
    for (; i < n4; i += stride) {
        float4 v = reinterpret_cast<const float4*>(in)[i];
        ushort4 o;
        o.x = f2bf(v.x); o.y = f2bf(v.y); o.z = f2bf(v.z); o.w = f2bf(v.w);
        reinterpret_cast<ushort4*>(out)[i] = o;
    }
}

// ---------- transpose + convert: in [K][N] f32 -> out [N][K] bf16 ----------
__global__ void k_transpose_bf16(const float* __restrict__ in, u16* __restrict__ out,
                                 int K, int N) {
    __shared__ float tile[32][33];
    int bn = blockIdx.x * 32;
    int bk = blockIdx.y * 32;
    int tx = threadIdx.x, ty = threadIdx.y;
#pragma unroll
    for (int i = 0; i < 32; i += 8)
        tile[ty + i][tx] = in[(size_t)(bk + ty + i) * N + bn + tx];
    __syncthreads();
#pragma unroll
    for (int i = 0; i < 32; i += 8)
        out[(size_t)(bn + ty + i) * K + bk + tx] = f2bf(tile[tx][ty + i]);
}

// ---------- GEMM: C[M,N] = A[M,K] * Bt[N,K]^T + bias ----------
// MODE 0: scatter q/k -> [B,H,T,D] bf16, v -> [B,H,D,T] bf16 (transposed)
// MODE 1: plain f32 out
template <int MODE>
__global__ __launch_bounds__(256, 2) void k_gemm_bt(
    const u16* __restrict__ A, const u16* __restrict__ Bt,
    const float* __restrict__ bias, void* __restrict__ outp,
    int M, int N, int K) {
    __shared__ __align__(16) u16 As[128 * 32];
    __shared__ __align__(16) u16 Bs[128 * 32];
    const int l = threadIdx.x & 63;
    const int w = threadIdx.x >> 6;
    const int m0 = blockIdx.x * 128;
    const int n0 = blockIdx.y * 128;
    const int wr = w >> 1, wc = w & 1;

    f32x4 acc[4][4] = {};
    const int nkt = K >> 5;
    for (int kt = 0; kt < nkt; ++kt) {
        __syncthreads();
#pragma unroll
        for (int i = 0; i < 2; ++i) {
            int c = w * 2 + i;
            const u16* gA = A + (size_t)(m0 + c * 16 + (l >> 2)) * K + (kt << 5) + (l & 3) * 8;
            const u16* gB = Bt + (size_t)(n0 + c * 16 + (l >> 2)) * K + (kt << 5) + (l & 3) * 8;
            GLD16(gA, As + c * 512);
            GLD16(gB, Bs + c * 512);
        }
        __syncthreads();
        bf16x8 af[4], bfr[4];
#pragma unroll
        for (int mi = 0; mi < 4; ++mi)
            af[mi] = *reinterpret_cast<const bf16x8*>(As + (wr * 64 + mi * 16 + (l & 15)) * 32 + (l >> 4) * 8);
#pragma unroll
        for (int ni = 0; ni < 4; ++ni)
            bfr[ni] = *reinterpret_cast<const bf16x8*>(Bs + (wc * 64 + ni * 16 + (l & 15)) * 32 + (l >> 4) * 8);
#pragma unroll
        for (int mi = 0; mi < 4; ++mi)
#pragma unroll
            for (int ni = 0; ni < 4; ++ni)
                acc[mi][ni] = __builtin_amdgcn_mfma_f32_16x16x32_bf16(af[mi], bfr[ni], acc[mi][ni], 0, 0, 0);
    }

    if (MODE == 1) {
        float* C = (float*)outp;
#pragma unroll
        for (int mi = 0; mi < 4; ++mi)
#pragma unroll
            for (int ni = 0; ni < 4; ++ni) {
                int n = n0 + wc * 64 + ni * 16 + (l & 15);
                float bv = bias[n];
#pragma unroll
                for (int r = 0; r < 4; ++r) {
                    int m = m0 + wr * 64 + mi * 16 + (l >> 4) * 4 + r;
                    C[(size_t)m * N + n] = acc[mi][ni][r] + bv;
                }
            }
    } else {
        u16* qkv = (u16*)outp;
        const size_t headsz = (size_t)BATCH * NH * TSEQ * HD;
#pragma unroll
        for (int mi = 0; mi < 4; ++mi)
#pragma unroll
            for (int ni = 0; ni < 4; ++ni) {
                int n = n0 + wc * 64 + ni * 16 + (l & 15);
                float bv = bias[n];
                int which = n >> 10;
                int c = n & 1023;
                int h = c >> 6, d = c & 63;
#pragma unroll
                for (int r = 0; r < 4; ++r) {
                    int m = m0 + wr * 64 + mi * 16 + (l >> 4) * 4 + r;
                    int b = m >> 11, t = m & 2047;
                    float v = acc[mi][ni][r] + bv;
                    size_t dst;
                    if (which == 2)  // V stored transposed: [B,H,D,T]
                        dst = 2 * headsz + ((size_t)(b * NH + h) * HD + d) * TSEQ + t;
                    else
                        dst = (size_t)which * headsz + ((size_t)(b * NH + h) * TSEQ + t) * HD + d;
                    qkv[dst] = f2bf(v);
                }
            }
    }
}

// ---------- causal flash attention, swapped-QK^T, P-in-reg, K-range split x2 ----------
// grid: 2048 blocks = 32 q-tiles x 2 k-halves x 32 bh, 4 waves, 32KB LDS
// (5 blocks/CU resident, 3/CU backfill queue). Block (t, half) processes
// contiguous K-tile range [ktLo,ktHi) (disjoint -> no extra staging traffic)
// and writes UNNORMALIZED partials (o bf16, m/l f32); k_merge combines.
__global__ __launch_bounds__(256, 4) void k_attn(
    const u16* __restrict__ qb, const u16* __restrict__ kb, const u16* __restrict__ vtb,
    u16* __restrict__ oPart, float* __restrict__ mlPart) {
    __shared__ __align__(16) u16 Ks[2][64 * 64];
    __shared__ __align__(16) u16 Vs[2][64 * 64];
    const int l = threadIdx.x & 63;
    const int w = threadIdx.x >> 6;
    const int g = l >> 4, l15 = l & 15;

    const int bid = blockIdx.x;
    const int t = 31 - (bid >> 6);        // q-tile index, heavy first
    const int half = (bid >> 5) & 1;
    const int bh = bid & 31;
    const int q0 = t * 64;
    const int nA = (t + 2) >> 1;          // ceil((t+1)/2)
    const int ktLo = half ? nA : 0;
    const int ktHi = half ? (t + 1) : nA;

    const size_t base = (size_t)bh * TSEQ * HD;
    const u16* Q = qb + base;
    const u16* Kg = kb + base;
    const u16* Vg = vtb + base;  // [64 d][2048 t]

    // staging lane decomposition: 8 rows x 8 chunks of 8 elems per 1KB call
    const int lrow8 = l >> 3;
    const int lchunk = (l & 7) ^ lrow8;  // inverse-swizzled source chunk

    const int qrow = q0 + w * 16 + l15;  // this lane's q-row
    bf16x8 qa[2];
    qa[0] = *reinterpret_cast<const bf16x8*>(Q + (size_t)qrow * HD + g * 8);
    qa[1] = *reinterpret_cast<const bf16x8*>(Q + (size_t)qrow * HD + 32 + g * 8);

    float mrow = -1e30f, lsum = 0.f;
    f32x4 o[4] = {};

    const float SC = 0.125f * 1.44269504f;  // log2(e)/sqrt(64)
    const float THRU = 44.3614f;            // 8/SC (defer-max threshold, unscaled)

    const int srcA = ((2 * g) & 3) * 16 + l15;
    const int srcB = ((2 * g + 1) & 3) * 16 + l15;
    const bool losel = (g < 2);

    if (ktLo < ktHi) {
        // prologue: stage tile ktLo into buffer 0
#pragma unroll
        for (int i2 = 0; i2 < 2; ++i2) {
            int c = w * 2 + i2;
            GLD16(Kg + (size_t)(ktLo * 64 + c * 8 + lrow8) * HD + lchunk * 8, &Ks[0][c * 512]);
            GLD16(Vg + (size_t)(c * 8 + lrow8) * TSEQ + ktLo * 64 + lchunk * 8, &Vs[0][c * 512]);
        }
        __syncthreads();

        int cur = 0;
        for (int kt = ktLo; kt < ktHi; ++kt) {
            if (kt + 1 < ktHi) {
                int nb = cur ^ 1;
#pragma unroll
                for (int i2 = 0; i2 < 2; ++i2) {
                    int c = w * 2 + i2;
                    GLD16(Kg + (size_t)((kt + 1) * 64 + c * 8 + lrow8) * HD + lchunk * 8,
                          &Ks[nb][c * 512]);
                    GLD16(Vg + (size_t)(c * 8 + lrow8) * TSEQ + (kt + 1) * 64 + lchunk * 8,
                          &Vs[nb][c * 512]);
                }
            }
            const u16* Kc = Ks[cur];
            const u16* Vc = Vs[cur];

            // S^T = mfma(A=K-frag, B=Q-frag): s[f][r] = S[q=qrow][k=kt*64+f*16+g*4+r]
            f32x4 s[4] = {};
            __builtin_amdgcn_s_setprio(1);
#pragma unroll
            for (int f = 0; f < 4; ++f)
#pragma unroll
                for (int ks = 0; ks < 2; ++ks) {
                    bf16x8 bk = *reinterpret_cast<const bf16x8*>(
                        Kc + (f * 16 + l15) * 64 + (((ks * 4 + g) ^ (l15 & 7)) * 8));
                    s[f] = __builtin_amdgcn_mfma_f32_16x16x32_bf16(bk, qa[ks], s[f], 0, 0, 0);
                }
            __builtin_amdgcn_s_setprio(0);

            // causal mask on diagonal tile (kt == t)
            if (kt == t) {
#pragma unroll
                for (int f = 0; f < 4; ++f)
#pragma unroll
                    for (int r = 0; r < 4; ++r) {
                        int kg = (kt << 6) + f * 16 + g * 4 + r;
                        if (kg > qrow) s[f][r] = -1e30f;
                    }
            }

            // lane-local softmax for row q=qrow
            float rmax = -1e30f;
#pragma unroll
            for (int f = 0; f < 4; ++f)
                rmax = fmaxf(rmax, fmaxf(fmaxf(s[f][0], s[f][1]), fmaxf(s[f][2], s[f][3])));
            rmax = fmaxf(rmax, __shfl_xor(rmax, 16));
            rmax = fmaxf(rmax, __shfl_xor(rmax, 32));

            if (__any(rmax - mrow > THRU)) {
                float mnew = fmaxf(mrow, rmax);
                float alpha = exp2f((mrow - mnew) * SC);
                mrow = mnew;
                lsum *= alpha;
#pragma unroll
                for (int nf = 0; nf < 4; ++nf)
#pragma unroll
                    for (int r = 0; r < 4; ++r)
                        o[nf][r] *= alpha;
            }
            const float mc = mrow * SC;

            float pe[4][4];
            float rsum = 0.f;
#pragma unroll
            for (int f = 0; f < 4; ++f)
#pragma unroll
                for (int r = 0; r < 4; ++r) {
                    float v = exp2f(__builtin_fmaf(s[f][r], SC, -mc));
                    pe[f][r] = v;
                    rsum += v;
                }
            rsum += __shfl_xor(rsum, 16);
            rsum += __shfl_xor(rsum, 32);
            lsum += rsum;

            // pack P to bf16
            u32 w0[4], w1[4];
#pragma unroll
            for (int f = 0; f < 4; ++f) {
                w0[f] = cvt_pk_bf16(pe[f][0], pe[f][1]);
                w1[f] = cvt_pk_bf16(pe[f][2], pe[f][3]);
            }

            // O^T += mfma(A=V^T-frag, B=P-frag)
            __builtin_amdgcn_s_setprio(1);
#pragma unroll
            for (int ks = 0; ks < 2; ++ks) {
                u32 t00 = (u32)__shfl((int)w0[2 * ks], srcA);
                u32 t01 = (u32)__shfl((int)w0[2 * ks + 1], srcA);
                u32 t10 = (u32)__shfl((int)w1[2 * ks], srcA);
                u32 t11 = (u32)__shfl((int)w1[2 * ks + 1], srcA);
                u32 t20 = (u32)__shfl((int)w0[2 * ks], srcB);
                u32 t21 = (u32)__shfl((int)w0[2 * ks + 1], srcB);
                u32 t30 = (u32)__shfl((int)w1[2 * ks], srcB);
                u32 t31 = (u32)__shfl((int)w1[2 * ks + 1], srcB);
                u32x4 bb;
                bb.x = losel ? t00 : t01;
                bb.y = losel ? t10 : t11;
                bb.z = losel ? t20 : t21;
                bb.w = losel ? t30 : t31;
                bf16x8 pb = __builtin_bit_cast(bf16x8, bb);
#pragma unroll
                for (int nf = 0; nf < 4; ++nf) {
                    bf16x8 bv = *reinterpret_cast<const bf16x8*>(
                        Vc + (nf * 16 + l15) * 64 + (((ks * 4 + g) ^ (l15 & 7)) * 8));
                    o[nf] = __builtin_amdgcn_mfma_f32_16x16x32_bf16(bv, pb, o[nf], 0, 0, 0);
                }
            }
            __builtin_amdgcn_s_setprio(0);
            __syncthreads();  // drains vmcnt (prefetch) + protects buffer reuse
            cur ^= 1;
        }
    }

    // partial epilogue: UNNORMALIZED o (bf16) + m, l (f32)
    const size_t oHalf = (size_t)32 * TSEQ * HD;
    u16* oRow = oPart + half * oHalf + ((size_t)bh * TSEQ + qrow) * HD;
#pragma unroll
    for (int nf = 0; nf < 4; ++nf) {
        int d0 = nf * 16 + g * 4;
        u32 p01 = cvt_pk_bf16(o[nf][0], o[nf][1]);
        u32 p23 = cvt_pk_bf16(o[nf][2], o[nf][3]);
        *reinterpret_cast<u32*>(oRow + d0) = p01;
        *reinterpret_cast<u32*>(oRow + d0 + 2) = p23;
    }
    if (g == 0) {
        float* mlH = mlPart + half * ((size_t)32 * 2 * TSEQ);
        mlH[((size_t)bh * 2 + 0) * TSEQ + qrow] = mrow;
        mlH[((size_t)bh * 2 + 1) * TSEQ + qrow] = lsum;
    }
}

// ---------- merge the two K-half partials -> attn [B*T][NE] bf16 ----------
__global__ void k_merge(const u16* __restrict__ oPart, const float* __restrict__ mlPart,
                        u16* __restrict__ attn_out) {
    const float SC = 0.125f * 1.44269504f;
    int tid = blockIdx.x * blockDim.x + threadIdx.x;  // 32*2048*8
    int dblk = tid & 7;
    int q = (tid >> 3) & 2047;
    int bh = tid >> 14;
    const size_t oHalf = (size_t)32 * TSEQ * HD;
    const size_t mlHalf = (size_t)32 * 2 * TSEQ;
    float mA = mlPart[((size_t)bh * 2 + 0) * TSEQ + q];
    float lA = mlPart[((size_t)bh * 2 + 1) * TSEQ + q];
    float mB = mlPart[mlHalf + ((size_t)bh * 2 + 0) * TSEQ + q];
    float lB = mlPart[mlHalf + ((size_t)bh * 2 + 1) * TSEQ + q];
    float M = fmaxf(mA, mB);
    float eA = exp2f((mA - M) * SC);
    float eB = exp2f((mB - M) * SC);
    float invL = 1.0f / (lA * eA + lB * eB);
    float fA = eA * invL, fB = eB * invL;
    const u32* pa = (const u32*)(oPart + ((size_t)bh * TSEQ + q) * HD + dblk * 8);
    const u32* pb = (const u32*)(oPart + oHalf + ((size_t)bh * TSEQ + q) * HD + dblk * 8);
    u32 outw[4];
#pragma unroll
    for (int i = 0; i < 4; ++i) {
        u32 a = pa[i], b = pb[i];
        float lo = bf2f(a & 0xffffu) * fA + bf2f(b & 0xffffu) * fB;
        float hi = bf2f(a >> 16) * fA + bf2f(b >> 16) * fB;
        outw[i] = cvt_pk_bf16(lo, hi);
    }
    int bb = bh >> 4, h = bh & 15;
    u16* dst = attn_out + ((size_t)(bb * TSEQ + q) * NE) + h * HD + dblk * 8;
    *reinterpret_cast<u32x4*>(dst) = *reinterpret_cast<const u32x4*>(outw);
}

extern "C" void kernel_launch(void* const* d_in, const int* in_sizes, int n_in,
                              void* d_out, int out_size, void* d_ws, size_t ws_size,
                              hipStream_t stream) {
    const float* x = (const float*)d_in[0];
    const float* W_attn = (const float*)d_in[1];
    const float* b_attn = (const float*)d_in[2];
    const float* W_proj = (const float*)d_in[3];
    const float* b_proj = (const float*)d_in[4];
    float* out = (float*)d_out;

    char* ws = (char*)d_ws;
    // layout (52MB total):
    //  0..8    xb   [4096,1024] bf16   (dead after QKV GEMM -> reused as oPart half A)
    //  8..14   WaT  [3072,1024] bf16   (dead after QKV GEMM -> reused as oPart half B)
    //  16..40  qkvb q,k [B,H,T,D], v [B,H,D,T] bf16
    //  40..48  attn [4096,1024] bf16
    //  48..50  WpT  [1024,1024] bf16
    //  50..52  mlPart [2][32][2][2048] f32
    u16* xb     = (u16*)(ws);
    u16* WaT    = (u16*)(ws + 8 * MB);
    u16* qkvb   = (u16*)(ws + 16 * MB);
    u16* attn   = (u16*)(ws + 40 * MB);
    u16* WpT    = (u16*)(ws + 48 * MB);
    float* mlP  = (float*)(ws + 50 * MB);
    u16* oPart  = (u16*)(ws);  // half A at 0..8MB, half B at 8..16MB

    const int M = BATCH * TSEQ;  // 4096

    k_f32_to_bf16<<<2048, 256, 0, stream>>>(x, xb, (M * NE) / 4);
    k_transpose_bf16<<<dim3(3 * NE / 32, NE / 32), dim3(32, 8), 0, stream>>>(W_attn, WaT, NE, 3 * NE);
    k_transpose_bf16<<<dim3(NE / 32, NE / 32), dim3(32, 8), 0, stream>>>(W_proj, WpT, NE, NE);

    k_gemm_bt<0><<<dim3(M / 128, (3 * NE) / 128), 256, 0, stream>>>(xb, WaT, b_attn, qkvb, M, 3 * NE, NE);

    const size_t headsz = (size_t)BATCH * NH * TSEQ * HD;  // 4M elems
    k_attn<<<dim3(32 * 2 * 32), 256, 0, stream>>>(qkvb, qkvb + headsz, qkvb + 2 * headsz, oPart, mlP);

    k_merge<<<dim3((32 * TSEQ * 8) / 256), 256, 0, stream>>>(oPart, mlP, attn);

    k_gemm_bt<1><<<dim3(M / 128, NE / 128), 256, 0, stream>>>(attn, WpT, b_proj, out, M, NE, NE);
}

// Round 9
// 129.883 us; speedup vs baseline: 1.0375x; 1.0021x over previous
//
#include <hip/hip_runtime.h>
#include <hip/hip_bf16.h>

#define NE 1024       // N_EMBD
#define NH 16         // N_HEAD
#define HD 64         // HEAD_SIZE
#define TSEQ 2048
#define BATCH 2
#define MB (1024u * 1024u)

typedef __attribute__((ext_vector_type(8))) short bf16x8;
typedef __attribute__((ext_vector_type(4))) float f32x4;
typedef __attribute__((ext_vector_type(4))) unsigned int u32x4;
typedef unsigned short u16;
typedef unsigned int u32;

__device__ inline u16 f2bf(float f) {
    __hip_bfloat16 h = __float2bfloat16(f);
    return *reinterpret_cast<u16*>(&h);
}

__device__ inline float bf2f(u32 bits) {
    u32 v = bits << 16;
    return __builtin_bit_cast(float, v);
}

__device__ inline u32 cvt_pk_bf16(float lo, float hi) {
    u32 r;
    asm("v_cvt_pk_bf16_f32 %0, %1, %2" : "=v"(r) : "v"(lo), "v"(hi));
    return r;
}

#define GLD16(gptr, lptr)                                                        \
    __builtin_amdgcn_global_load_lds(                                            \
        (const __attribute__((address_space(1))) void*)(gptr),                   \
        (__attribute__((address_space(3))) void*)(lptr), 16, 0, 0)

// ---------- elementwise f32 -> bf16 ----------
__global__ void k_f32_to_bf16(const float* __restrict__ in, u16* __restrict__ out, int n4) {
    int i = blockIdx.x * blockDim.x + threadIdx.x;
    int stride = gridDim.x * blockDim.x;
    for (; i < n4; i += stride) {
        float4 v = reinterpret_cast<const float4*>(in)[i];
        ushort4 o;
        o.x = f2bf(v.x); o.y = f2bf(v.y); o.z = f2bf(v.z); o.w = f2bf(v.w);
        reinterpret_cast<ushort4*>(out)[i] = o;
    }
}

// ---------- transpose + convert: in [K][N] f32 -> out [N][K] bf16 ----------
__global__ void k_transpose_bf16(const float* __restrict__ in, u16* __restrict__ out,
                                 int K, int N) {
    __shared__ float tile[32][33];
    int bn = blockIdx.x * 32;
    int bk = blockIdx.y * 32;
    int tx = threadIdx.x, ty = threadIdx.y;
#pragma unroll
    for (int i = 0; i < 32; i += 8)
        tile[ty + i][tx] = in[(size_t)(bk + ty + i) * N + bn + tx];
    __syncthreads();
#pragma unroll
    for (int i = 0; i < 32; i += 8)
        out[(size_t)(bn + ty + i) * K + bk + tx] = f2bf(tile[tx][ty + i]);
}

// ---------- GEMM: C[M,N] = A[M,K] * Bt[N,K]^T + bias ----------
// Double-buffered LDS (T3-minimum): prefetch tile kt+1 before computing kt,
// single barrier per K-step.
// MODE 0: scatter q/k -> [B,H,T,D] bf16, v -> [B,H,D,T] bf16 (transposed)
// MODE 1: plain f32 out
template <int MODE>
__global__ __launch_bounds__(256, 2) void k_gemm_bt(
    const u16* __restrict__ A, const u16* __restrict__ Bt,
    const float* __restrict__ bias, void* __restrict__ outp,
    int M, int N, int K) {
    __shared__ __align__(16) u16 As[2][128 * 32];
    __shared__ __align__(16) u16 Bs[2][128 * 32];
    const int l = threadIdx.x & 63;
    const int w = threadIdx.x >> 6;
    const int m0 = blockIdx.x * 128;
    const int n0 = blockIdx.y * 128;
    const int wr = w >> 1, wc = w & 1;
    const int srow = l >> 2;           // staging row within 16-row chunk
    const int scol = (l & 3) * 8;      // staging k-offset (8 u16 = 16B)

    f32x4 acc[4][4] = {};
    const int nkt = K >> 5;

    // prologue: stage kt=0 into buffer 0
#pragma unroll
    for (int i = 0; i < 2; ++i) {
        int c = w * 2 + i;
        GLD16(A + (size_t)(m0 + c * 16 + srow) * K + scol, &As[0][c * 512]);
        GLD16(Bt + (size_t)(n0 + c * 16 + srow) * K + scol, &Bs[0][c * 512]);
    }
    __syncthreads();

    int cur = 0;
    for (int kt = 0; kt < nkt; ++kt) {
        // prefetch next K-tile into the other buffer (overlaps with MFMA)
        if (kt + 1 < nkt) {
            int nb = cur ^ 1;
            int kc = ((kt + 1) << 5) + scol;
#pragma unroll
            for (int i = 0; i < 2; ++i) {
                int c = w * 2 + i;
                GLD16(A + (size_t)(m0 + c * 16 + srow) * K + kc, &As[nb][c * 512]);
                GLD16(Bt + (size_t)(n0 + c * 16 + srow) * K + kc, &Bs[nb][c * 512]);
            }
        }
        bf16x8 af[4], bfr[4];
#pragma unroll
        for (int mi = 0; mi < 4; ++mi)
            af[mi] = *reinterpret_cast<const bf16x8*>(
                &As[cur][(wr * 64 + mi * 16 + (l & 15)) * 32 + (l >> 4) * 8]);
#pragma unroll
        for (int ni = 0; ni < 4; ++ni)
            bfr[ni] = *reinterpret_cast<const bf16x8*>(
                &Bs[cur][(wc * 64 + ni * 16 + (l & 15)) * 32 + (l >> 4) * 8]);
#pragma unroll
        for (int mi = 0; mi < 4; ++mi)
#pragma unroll
            for (int ni = 0; ni < 4; ++ni)
                acc[mi][ni] = __builtin_amdgcn_mfma_f32_16x16x32_bf16(af[mi], bfr[ni], acc[mi][ni], 0, 0, 0);
        __syncthreads();  // drains prefetch vmcnt + protects buffer reuse
        cur ^= 1;
    }

    if (MODE == 1) {
        float* C = (float*)outp;
#pragma unroll
        for (int mi = 0; mi < 4; ++mi)
#pragma unroll
            for (int ni = 0; ni < 4; ++ni) {
                int n = n0 + wc * 64 + ni * 16 + (l & 15);
                float bv = bias[n];
#pragma unroll
                for (int r = 0; r < 4; ++r) {
                    int m = m0 + wr * 64 + mi * 16 + (l >> 4) * 4 + r;
                    C[(size_t)m * N + n] = acc[mi][ni][r] + bv;
                }
            }
    } else {
        u16* qkv = (u16*)outp;
        const size_t headsz = (size_t)BATCH * NH * TSEQ * HD;
#pragma unroll
        for (int mi = 0; mi < 4; ++mi)
#pragma unroll
            for (int ni = 0; ni < 4; ++ni) {
                int n = n0 + wc * 64 + ni * 16 + (l & 15);
                float bv = bias[n];
                int which = n >> 10;
                int c = n & 1023;
                int h = c >> 6, d = c & 63;
#pragma unroll
                for (int r = 0; r < 4; ++r) {
                    int m = m0 + wr * 64 + mi * 16 + (l >> 4) * 4 + r;
                    int b = m >> 11, t = m & 2047;
                    float v = acc[mi][ni][r] + bv;
                    size_t dst;
                    if (which == 2)  // V stored transposed: [B,H,D,T]
                        dst = 2 * headsz + ((size_t)(b * NH + h) * HD + d) * TSEQ + t;
                    else
                        dst = (size_t)which * headsz + ((size_t)(b * NH + h) * TSEQ + t) * HD + d;
                    qkv[dst] = f2bf(v);
                }
            }
    }
}

// ---------- causal flash attention, swapped-QK^T, P-in-reg, K-range split x2 ----------
// grid: 2048 blocks = 32 q-tiles x 2 k-halves x 32 bh, 4 waves, 32KB LDS
// (5 blocks/CU resident, 3/CU backfill queue). Block (t, half) processes
// contiguous K-tile range [ktLo,ktHi) (disjoint -> no extra staging traffic)
// and writes UNNORMALIZED partials (o bf16, m/l f32); k_merge combines.
__global__ __launch_bounds__(256, 4) void k_attn(
    const u16* __restrict__ qb, const u16* __restrict__ kb, const u16* __restrict__ vtb,
    u16* __restrict__ oPart, float* __restrict__ mlPart) {
    __shared__ __align__(16) u16 Ks[2][64 * 64];
    __shared__ __align__(16) u16 Vs[2][64 * 64];
    const int l = threadIdx.x & 63;
    const int w = threadIdx.x >> 6;
    const int g = l >> 4, l15 = l & 15;

    const int bid = blockIdx.x;
    const int t = 31 - (bid >> 6);        // q-tile index, heavy first
    const int half = (bid >> 5) & 1;
    const int bh = bid & 31;
    const int q0 = t * 64;
    const int nA = (t + 2) >> 1;          // ceil((t+1)/2)
    const int ktLo = half ? nA : 0;
    const int ktHi = half ? (t + 1) : nA;

    const size_t base = (size_t)bh * TSEQ * HD;
    const u16* Q = qb + base;
    const u16* Kg = kb + base;
    const u16* Vg = vtb + base;  // [64 d][2048 t]

    // staging lane decomposition: 8 rows x 8 chunks of 8 elems per 1KB call
    const int lrow8 = l >> 3;
    const int lchunk = (l & 7) ^ lrow8;  // inverse-swizzled source chunk

    const int qrow = q0 + w * 16 + l15;  // this lane's q-row
    bf16x8 qa[2];
    qa[0] = *reinterpret_cast<const bf16x8*>(Q + (size_t)qrow * HD + g * 8);
    qa[1] = *reinterpret_cast<const bf16x8*>(Q + (size_t)qrow * HD + 32 + g * 8);

    float mrow = -1e30f, lsum = 0.f;
    f32x4 o[4] = {};

    const float SC = 0.125f * 1.44269504f;  // log2(e)/sqrt(64)
    const float THRU = 44.3614f;            // 8/SC (defer-max threshold, unscaled)

    const int srcA = ((2 * g) & 3) * 16 + l15;
    const int srcB = ((2 * g + 1) & 3) * 16 + l15;
    const bool losel = (g < 2);

    if (ktLo < ktHi) {
        // prologue: stage tile ktLo into buffer 0
#pragma unroll
        for (int i2 = 0; i2 < 2; ++i2) {
            int c = w * 2 + i2;
            GLD16(Kg + (size_t)(ktLo * 64 + c * 8 + lrow8) * HD + lchunk * 8, &Ks[0][c * 512]);
            GLD16(Vg + (size_t)(c * 8 + lrow8) * TSEQ + ktLo * 64 + lchunk * 8, &Vs[0][c * 512]);
        }
        __syncthreads();

        int cur = 0;
        for (int kt = ktLo; kt < ktHi; ++kt) {
            if (kt + 1 < ktHi) {
                int nb = cur ^ 1;
#pragma unroll
                for (int i2 = 0; i2 < 2; ++i2) {
                    int c = w * 2 + i2;
                    GLD16(Kg + (size_t)((kt + 1) * 64 + c * 8 + lrow8) * HD + lchunk * 8,
                          &Ks[nb][c * 512]);
                    GLD16(Vg + (size_t)(c * 8 + lrow8) * TSEQ + (kt + 1) * 64 + lchunk * 8,
                          &Vs[nb][c * 512]);
                }
            }
            const u16* Kc = Ks[cur];
            const u16* Vc = Vs[cur];

            // S^T = mfma(A=K-frag, B=Q-frag): s[f][r] = S[q=qrow][k=kt*64+f*16+g*4+r]
            f32x4 s[4] = {};
            __builtin_amdgcn_s_setprio(1);
#pragma unroll
            for (int f = 0; f < 4; ++f)
#pragma unroll
                for (int ks = 0; ks < 2; ++ks) {
                    bf16x8 bk = *reinterpret_cast<const bf16x8*>(
                        Kc + (f * 16 + l15) * 64 + (((ks * 4 + g) ^ (l15 & 7)) * 8));
                    s[f] = __builtin_amdgcn_mfma_f32_16x16x32_bf16(bk, qa[ks], s[f], 0, 0, 0);
                }
            __builtin_amdgcn_s_setprio(0);

            // causal mask on diagonal tile (kt == t)
            if (kt == t) {
#pragma unroll
                for (int f = 0; f < 4; ++f)
#pragma unroll
                    for (int r = 0; r < 4; ++r) {
                        int kg = (kt << 6) + f * 16 + g * 4 + r;
                        if (kg > qrow) s[f][r] = -1e30f;
                    }
            }

            // lane-local softmax for row q=qrow
            float rmax = -1e30f;
#pragma unroll
            for (int f = 0; f < 4; ++f)
                rmax = fmaxf(rmax, fmaxf(fmaxf(s[f][0], s[f][1]), fmaxf(s[f][2], s[f][3])));
            rmax = fmaxf(rmax, __shfl_xor(rmax, 16));
            rmax = fmaxf(rmax, __shfl_xor(rmax, 32));

            if (__any(rmax - mrow > THRU)) {
                float mnew = fmaxf(mrow, rmax);
                float alpha = exp2f((mrow - mnew) * SC);
                mrow = mnew;
                lsum *= alpha;
#pragma unroll
                for (int nf = 0; nf < 4; ++nf)
#pragma unroll
                    for (int r = 0; r < 4; ++r)
                        o[nf][r] *= alpha;
            }
            const float mc = mrow * SC;

            float pe[4][4];
            float rsum = 0.f;
#pragma unroll
            for (int f = 0; f < 4; ++f)
#pragma unroll
                for (int r = 0; r < 4; ++r) {
                    float v = exp2f(__builtin_fmaf(s[f][r], SC, -mc));
                    pe[f][r] = v;
                    rsum += v;
                }
            rsum += __shfl_xor(rsum, 16);
            rsum += __shfl_xor(rsum, 32);
            lsum += rsum;

            // pack P to bf16
            u32 w0[4], w1[4];
#pragma unroll
            for (int f = 0; f < 4; ++f) {
                w0[f] = cvt_pk_bf16(pe[f][0], pe[f][1]);
                w1[f] = cvt_pk_bf16(pe[f][2], pe[f][3]);
            }

            // O^T += mfma(A=V^T-frag, B=P-frag)
            __builtin_amdgcn_s_setprio(1);
#pragma unroll
            for (int ks = 0; ks < 2; ++ks) {
                u32 t00 = (u32)__shfl((int)w0[2 * ks], srcA);
                u32 t01 = (u32)__shfl((int)w0[2 * ks + 1], srcA);
                u32 t10 = (u32)__shfl((int)w1[2 * ks], srcA);
                u32 t11 = (u32)__shfl((int)w1[2 * ks + 1], srcA);
                u32 t20 = (u32)__shfl((int)w0[2 * ks], srcB);
                u32 t21 = (u32)__shfl((int)w0[2 * ks + 1], srcB);
                u32 t30 = (u32)__shfl((int)w1[2 * ks], srcB);
                u32 t31 = (u32)__shfl((int)w1[2 * ks + 1], srcB);
                u32x4 bb;
                bb.x = losel ? t00 : t01;
                bb.y = losel ? t10 : t11;
                bb.z = losel ? t20 : t21;
                bb.w = losel ? t30 : t31;
                bf16x8 pb = __builtin_bit_cast(bf16x8, bb);
#pragma unroll
                for (int nf = 0; nf < 4; ++nf) {
                    bf16x8 bv = *reinterpret_cast<const bf16x8*>(
                        Vc + (nf * 16 + l15) * 64 + (((ks * 4 + g) ^ (l15 & 7)) * 8));
                    o[nf] = __builtin_amdgcn_mfma_f32_16x16x32_bf16(bv, pb, o[nf], 0, 0, 0);
                }
            }
            __builtin_amdgcn_s_setprio(0);
            __syncthreads();  // drains vmcnt (prefetch) + protects buffer reuse
            cur ^= 1;
        }
    }

    // partial epilogue: UNNORMALIZED o (bf16) + m, l (f32)
    const size_t oHalf = (size_t)32 * TSEQ * HD;
    u16* oRow = oPart + half * oHalf + ((size_t)bh * TSEQ + qrow) * HD;
#pragma unroll
    for (int nf = 0; nf < 4; ++nf) {
        int d0 = nf * 16 + g * 4;
        u32 p01 = cvt_pk_bf16(o[nf][0], o[nf][1]);
        u32 p23 = cvt_pk_bf16(o[nf][2], o[nf][3]);
        *reinterpret_cast<u32*>(oRow + d0) = p01;
        *reinterpret_cast<u32*>(oRow + d0 + 2) = p23;
    }
    if (g == 0) {
        float* mlH = mlPart + half * ((size_t)32 * 2 * TSEQ);
        mlH[((size_t)bh * 2 + 0) * TSEQ + qrow] = mrow;
        mlH[((size_t)bh * 2 + 1) * TSEQ + qrow] = lsum;
    }
}

// ---------- merge the two K-half partials -> attn [B*T][NE] bf16 ----------
__global__ void k_merge(const u16* __restrict__ oPart, const float* __restrict__ mlPart,
                        u16* __restrict__ attn_out) {
    const float SC = 0.125f * 1.44269504f;
    int tid = blockIdx.x * blockDim.x + threadIdx.x;  // 32*2048*8
    int dblk = tid & 7;
    int q = (tid >> 3) & 2047;
    int bh = tid >> 14;
    const size_t oHalf = (size_t)32 * TSEQ * HD;
    const size_t mlHalf = (size_t)32 * 2 * TSEQ;
    float mA = mlPart[((size_t)bh * 2 + 0) * TSEQ + q];
    float lA = mlPart[((size_t)bh * 2 + 1) * TSEQ + q];
    float mB = mlPart[mlHalf + ((size_t)bh * 2 + 0) * TSEQ + q];
    float lB = mlPart[mlHalf + ((size_t)bh * 2 + 1) * TSEQ + q];
    float M = fmaxf(mA, mB);
    float eA = exp2f((mA - M) * SC);
    float eB = exp2f((mB - M) * SC);
    float invL = 1.0f / (lA * eA + lB * eB);
    float fA = eA * invL, fB = eB * invL;
    const u32* pa = (const u32*)(oPart + ((size_t)bh * TSEQ + q) * HD + dblk * 8);
    const u32* pb = (const u32*)(oPart + oHalf + ((size_t)bh * TSEQ + q) * HD + dblk * 8);
    u32 outw[4];
#pragma unroll
    for (int i = 0; i < 4; ++i) {
        u32 a = pa[i], b = pb[i];
        float lo = bf2f(a & 0xffffu) * fA + bf2f(b & 0xffffu) * fB;
        float hi = bf2f(a >> 16) * fA + bf2f(b >> 16) * fB;
        outw[i] = cvt_pk_bf16(lo, hi);
    }
    int bb = bh >> 4, h = bh & 15;
    u16* dst = attn_out + ((size_t)(bb * TSEQ + q) * NE) + h * HD + dblk * 8;
    *reinterpret_cast<u32x4*>(dst) = *reinterpret_cast<const u32x4*>(outw);
}

extern "C" void kernel_launch(void* const* d_in, const int* in_sizes, int n_in,
                              void* d_out, int out_size, void* d_ws, size_t ws_size,
                              hipStream_t stream) {
    const float* x = (const float*)d_in[0];
    const float* W_attn = (const float*)d_in[1];
    const float* b_attn = (const float*)d_in[2];
    const float* W_proj = (const float*)d_in[3];
    const float* b_proj = (const float*)d_in[4];
    float* out = (float*)d_out;

    char* ws = (char*)d_ws;
    // layout (52MB total):
    //  0..8    xb   [4096,1024] bf16   (dead after QKV GEMM -> reused as oPart half A)
    //  8..14   WaT  [3072,1024] bf16   (dead after QKV GEMM -> reused as oPart half B)
    //  16..40  qkvb q,k [B,H,T,D], v [B,H,D,T] bf16
    //  40..48  attn [4096,1024] bf16
    //  48..50  WpT  [1024,1024] bf16
    //  50..52  mlPart [2][32][2][2048] f32
    u16* xb     = (u16*)(ws);
    u16* WaT    = (u16*)(ws + 8 * MB);
    u16* qkvb   = (u16*)(ws + 16 * MB);
    u16* attn   = (u16*)(ws + 40 * MB);
    u16* WpT    = (u16*)(ws + 48 * MB);
    float* mlP  = (float*)(ws + 50 * MB);
    u16* oPart  = (u16*)(ws);  // half A at 0..8MB, half B at 8..16MB

    const int M = BATCH * TSEQ;  // 4096

    k_f32_to_bf16<<<2048, 256, 0, stream>>>(x, xb, (M * NE) / 4);
    k_transpose_bf16<<<dim3(3 * NE / 32, NE / 32), dim3(32, 8), 0, stream>>>(W_attn, WaT, NE, 3 * NE);
    k_transpose_bf16<<<dim3(NE / 32, NE / 32), dim3(32, 8), 0, stream>>>(W_proj, WpT, NE, NE);

    k_gemm_bt<0><<<dim3(M / 128, (3 * NE) / 128), 256, 0, stream>>>(xb, WaT, b_attn, qkvb, M, 3 * NE, NE);

    const size_t headsz = (size_t)BATCH * NH * TSEQ * HD;  // 4M elems
    k_attn<<<dim3(32 * 2 * 32), 256, 0, stream>>>(qkvb, qkvb + headsz, qkvb + 2 * headsz, oPart, mlP);

    k_merge<<<dim3((32 * TSEQ * 8) / 256), 256, 0, stream>>>(oPart, mlP, attn);

    k_gemm_bt<1><<<dim3(M / 128, NE / 128), 256, 0, stream>>>(attn, WpT, b_proj, out, M, NE, NE);
}

// Round 10
// 125.269 us; speedup vs baseline: 1.0757x; 1.0368x over previous
//
#include <hip/hip_runtime.h>
#include <hip/hip_bf16.h>

#define NE 1024       // N_EMBD
#define NH 16         // N_HEAD
#define HD 64         // HEAD_SIZE
#define TSEQ 2048
#define BATCH 2
#define MB (1024u * 1024u)

typedef __attribute__((ext_vector_type(8))) short bf16x8;
typedef __attribute__((ext_vector_type(4))) float f32x4;
typedef __attribute__((ext_vector_type(4))) unsigned int u32x4;
typedef unsigned short u16;
typedef unsigned int u32;

__device__ inline u16 f2bf(float f) {
    __hip_bfloat16 h = __float2bfloat16(f);
    return *reinterpret_cast<u16*>(&h);
}

__device__ inline float bf2f(u32 bits) {
    u32 v = bits << 16;
    return __builtin_bit_cast(float, v);
}

__device__ inline u32 cvt_pk_bf16(float lo, float hi) {
    u32 r;
    asm("v_cvt_pk_bf16_f32 %0, %1, %2" : "=v"(r) : "v"(lo), "v"(hi));
    return r;
}

#define GLD16(gptr, lptr)                                                        \
    __builtin_amdgcn_global_load_lds(                                            \
        (const __attribute__((address_space(1))) void*)(gptr),                   \
        (__attribute__((address_space(3))) void*)(lptr), 16, 0, 0)

// ---------- elementwise f32 -> bf16 ----------
__global__ void k_f32_to_bf16(const float* __restrict__ in, u16* __restrict__ out, int n4) {
    int i = blockIdx.x * blockDim.x + threadIdx.x;
    int stride = gridDim.x * blockDim.x;
    for (; i < n4; i += stride) {
        float4 v = reinterpret_cast<const float4*>(in)[i];
        ushort4 o;
        o.x = f2bf(v.x); o.y = f2bf(v.y); o.z = f2bf(v.z); o.w = f2bf(v.w);
        reinterpret_cast<ushort4*>(out)[i] = o;
    }
}

// ---------- combined transpose+convert for BOTH weights ----------
// blockIdx.x < 96: W_attn [1024][3072] -> WaT [3072][1024]
// else:            W_proj [1024][1024] -> WpT [1024][1024]
__global__ void k_prep_w(const float* __restrict__ Wa, const float* __restrict__ Wp,
                         u16* __restrict__ WaT, u16* __restrict__ WpT) {
    __shared__ float tile[32][33];
    const bool isA = blockIdx.x < 96;
    const float* in = isA ? Wa : Wp;
    u16* out = isA ? WaT : WpT;
    const int N = isA ? 3 * NE : NE;
    const int K = NE;
    int bn = (isA ? blockIdx.x : blockIdx.x - 96) * 32;
    int bk = blockIdx.y * 32;
    int tx = threadIdx.x, ty = threadIdx.y;
#pragma unroll
    for (int i = 0; i < 32; i += 8)
        tile[ty + i][tx] = in[(size_t)(bk + ty + i) * N + bn + tx];
    __syncthreads();
#pragma unroll
    for (int i = 0; i < 32; i += 8)
        out[(size_t)(bn + ty + i) * K + bk + tx] = f2bf(tile[tx][ty + i]);
}

// ---------- GEMM: C[M,N] = A[M,K] * Bt[N,K]^T + bias ----------
// Double-buffered LDS; prefetch kt+1 before computing kt, 1 barrier per K-step.
// MODE 0: scatter q/k -> [B,H,T,D] bf16, v -> [B,H,D,T] bf16 (transposed)
// MODE 1: plain f32 out
template <int MODE>
__global__ __launch_bounds__(256, 2) void k_gemm_bt(
    const u16* __restrict__ A, const u16* __restrict__ Bt,
    const float* __restrict__ bias, void* __restrict__ outp,
    int M, int N, int K) {
    __shared__ __align__(16) u16 As[2][128 * 32];
    __shared__ __align__(16) u16 Bs[2][128 * 32];
    const int l = threadIdx.x & 63;
    const int w = threadIdx.x >> 6;
    const int m0 = blockIdx.x * 128;
    const int n0 = blockIdx.y * 128;
    const int wr = w >> 1, wc = w & 1;
    const int srow = l >> 2;           // staging row within 16-row chunk
    const int scol = (l & 3) * 8;      // staging k-offset (8 u16 = 16B)

    f32x4 acc[4][4] = {};
    const int nkt = K >> 5;

    // prologue: stage kt=0 into buffer 0
#pragma unroll
    for (int i = 0; i < 2; ++i) {
        int c = w * 2 + i;
        GLD16(A + (size_t)(m0 + c * 16 + srow) * K + scol, &As[0][c * 512]);
        GLD16(Bt + (size_t)(n0 + c * 16 + srow) * K + scol, &Bs[0][c * 512]);
    }
    __syncthreads();

    int cur = 0;
    for (int kt = 0; kt < nkt; ++kt) {
        if (kt + 1 < nkt) {
            int nb = cur ^ 1;
            int kc = ((kt + 1) << 5) + scol;
#pragma unroll
            for (int i = 0; i < 2; ++i) {
                int c = w * 2 + i;
                GLD16(A + (size_t)(m0 + c * 16 + srow) * K + kc, &As[nb][c * 512]);
                GLD16(Bt + (size_t)(n0 + c * 16 + srow) * K + kc, &Bs[nb][c * 512]);
            }
        }
        bf16x8 af[4], bfr[4];
#pragma unroll
        for (int mi = 0; mi < 4; ++mi)
            af[mi] = *reinterpret_cast<const bf16x8*>(
                &As[cur][(wr * 64 + mi * 16 + (l & 15)) * 32 + (l >> 4) * 8]);
#pragma unroll
        for (int ni = 0; ni < 4; ++ni)
            bfr[ni] = *reinterpret_cast<const bf16x8*>(
                &Bs[cur][(wc * 64 + ni * 16 + (l & 15)) * 32 + (l >> 4) * 8]);
#pragma unroll
        for (int mi = 0; mi < 4; ++mi)
#pragma unroll
            for (int ni = 0; ni < 4; ++ni)
                acc[mi][ni] = __builtin_amdgcn_mfma_f32_16x16x32_bf16(af[mi], bfr[ni], acc[mi][ni], 0, 0, 0);
        __syncthreads();  // drains prefetch vmcnt + protects buffer reuse
        cur ^= 1;
    }

    if (MODE == 1) {
        float* C = (float*)outp;
#pragma unroll
        for (int mi = 0; mi < 4; ++mi)
#pragma unroll
            for (int ni = 0; ni < 4; ++ni) {
                int n = n0 + wc * 64 + ni * 16 + (l & 15);
                float bv = bias[n];
#pragma unroll
                for (int r = 0; r < 4; ++r) {
                    int m = m0 + wr * 64 + mi * 16 + (l >> 4) * 4 + r;
                    C[(size_t)m * N + n] = acc[mi][ni][r] + bv;
                }
            }
    } else {
        u16* qkv = (u16*)outp;
        const size_t headsz = (size_t)BATCH * NH * TSEQ * HD;
#pragma unroll
        for (int mi = 0; mi < 4; ++mi)
#pragma unroll
            for (int ni = 0; ni < 4; ++ni) {
                int n = n0 + wc * 64 + ni * 16 + (l & 15);
                float bv = bias[n];
                int which = n >> 10;
                int c = n & 1023;
                int h = c >> 6, d = c & 63;
#pragma unroll
                for (int r = 0; r < 4; ++r) {
                    int m = m0 + wr * 64 + mi * 16 + (l >> 4) * 4 + r;
                    int b = m >> 11, t = m & 2047;
                    float v = acc[mi][ni][r] + bv;
                    size_t dst;
                    if (which == 2)  // V stored transposed: [B,H,D,T]
                        dst = 2 * headsz + ((size_t)(b * NH + h) * HD + d) * TSEQ + t;
                    else
                        dst = (size_t)which * headsz + ((size_t)(b * NH + h) * TSEQ + t) * HD + d;
                    qkv[dst] = f2bf(v);
                }
            }
    }
}

// ---------- causal flash attention, swapped-QK^T, P-in-reg, K-range split x2 ----------
// grid: 2048 blocks = 32 q-tiles x 2 k-halves x 32 bh, 4 waves, 32KB LDS.
// Block (t, half) processes contiguous K-tile range [ktLo,ktHi) and writes
// UNNORMALIZED partials (o bf16, m/l f32); k_merge combines.
// Row-sum l is accumulated via an all-ones A-frag MFMA (os), not VALU adds.
__global__ __launch_bounds__(256, 4) void k_attn(
    const u16* __restrict__ qb, const u16* __restrict__ kb, const u16* __restrict__ vtb,
    u16* __restrict__ oPart, float* __restrict__ mlPart) {
    __shared__ __align__(16) u16 Ks[2][64 * 64];
    __shared__ __align__(16) u16 Vs[2][64 * 64];
    const int l = threadIdx.x & 63;
    const int w = threadIdx.x >> 6;
    const int g = l >> 4, l15 = l & 15;

    const int bid = blockIdx.x;
    const int t = 31 - (bid >> 6);        // q-tile index, heavy first
    const int half = (bid >> 5) & 1;
    const int bh = bid & 31;
    const int q0 = t * 64;
    const int nA = (t + 2) >> 1;          // ceil((t+1)/2)
    const int ktLo = half ? nA : 0;
    const int ktHi = half ? (t + 1) : nA;

    const size_t base = (size_t)bh * TSEQ * HD;
    const u16* Q = qb + base;
    const u16* Kg = kb + base;
    const u16* Vg = vtb + base;  // [64 d][2048 t]

    // staging lane decomposition: 8 rows x 8 chunks of 8 elems per 1KB call
    const int lrow8 = l >> 3;
    const int lchunk = (l & 7) ^ lrow8;  // inverse-swizzled source chunk

    const int qrow = q0 + w * 16 + l15;  // this lane's q-row
    bf16x8 qa[2];
    qa[0] = *reinterpret_cast<const bf16x8*>(Q + (size_t)qrow * HD + g * 8);
    qa[1] = *reinterpret_cast<const bf16x8*>(Q + (size_t)qrow * HD + 32 + g * 8);

    float mrow = -1e30f;
    f32x4 o[4] = {};
    f32x4 os = {};  // ones-MFMA row-sum accumulator; os[r] == lsum for q=l15

    const float SC = 0.125f * 1.44269504f;  // log2(e)/sqrt(64)
    const float THRU = 44.3614f;            // 8/SC (defer-max threshold, unscaled)

    const int srcA = ((2 * g) & 3) * 16 + l15;
    const int srcB = ((2 * g + 1) & 3) * 16 + l15;
    const bool losel = (g < 2);

    // all-ones bf16 A-frag (1.0 = 0x3F80)
    u32x4 onesw = {0x3F803F80u, 0x3F803F80u, 0x3F803F80u, 0x3F803F80u};
    const bf16x8 onesA = __builtin_bit_cast(bf16x8, onesw);

    if (ktLo < ktHi) {
        // prologue: stage tile ktLo into buffer 0
#pragma unroll
        for (int i2 = 0; i2 < 2; ++i2) {
            int c = w * 2 + i2;
            GLD16(Kg + (size_t)(ktLo * 64 + c * 8 + lrow8) * HD + lchunk * 8, &Ks[0][c * 512]);
            GLD16(Vg + (size_t)(c * 8 + lrow8) * TSEQ + ktLo * 64 + lchunk * 8, &Vs[0][c * 512]);
        }
        __syncthreads();

        int cur = 0;
        for (int kt = ktLo; kt < ktHi; ++kt) {
            if (kt + 1 < ktHi) {
                int nb = cur ^ 1;
#pragma unroll
                for (int i2 = 0; i2 < 2; ++i2) {
                    int c = w * 2 + i2;
                    GLD16(Kg + (size_t)((kt + 1) * 64 + c * 8 + lrow8) * HD + lchunk * 8,
                          &Ks[nb][c * 512]);
                    GLD16(Vg + (size_t)(c * 8 + lrow8) * TSEQ + (kt + 1) * 64 + lchunk * 8,
                          &Vs[nb][c * 512]);
                }
            }
            const u16* Kc = Ks[cur];
            const u16* Vc = Vs[cur];

            // S^T = mfma(A=K-frag, B=Q-frag): s[f][r] = S[q=qrow][k=kt*64+f*16+g*4+r]
            f32x4 s[4] = {};
            __builtin_amdgcn_s_setprio(1);
#pragma unroll
            for (int f = 0; f < 4; ++f)
#pragma unroll
                for (int ks = 0; ks < 2; ++ks) {
                    bf16x8 bk = *reinterpret_cast<const bf16x8*>(
                        Kc + (f * 16 + l15) * 64 + (((ks * 4 + g) ^ (l15 & 7)) * 8));
                    s[f] = __builtin_amdgcn_mfma_f32_16x16x32_bf16(bk, qa[ks], s[f], 0, 0, 0);
                }
            __builtin_amdgcn_s_setprio(0);

            // causal mask on diagonal tile (kt == t)
            if (kt == t) {
#pragma unroll
                for (int f = 0; f < 4; ++f)
#pragma unroll
                    for (int r = 0; r < 4; ++r) {
                        int kg = (kt << 6) + f * 16 + g * 4 + r;
                        if (kg > qrow) s[f][r] = -1e30f;
                    }
            }

            // lane-local max for row q=qrow
            float rmax = -1e30f;
#pragma unroll
            for (int f = 0; f < 4; ++f)
                rmax = fmaxf(rmax, fmaxf(fmaxf(s[f][0], s[f][1]), fmaxf(s[f][2], s[f][3])));
            rmax = fmaxf(rmax, __shfl_xor(rmax, 16));
            rmax = fmaxf(rmax, __shfl_xor(rmax, 32));

            if (__any(rmax - mrow > THRU)) {
                float mnew = fmaxf(mrow, rmax);
                float alpha = exp2f((mrow - mnew) * SC);
                mrow = mnew;
#pragma unroll
                for (int r = 0; r < 4; ++r)
                    os[r] *= alpha;
#pragma unroll
                for (int nf = 0; nf < 4; ++nf)
#pragma unroll
                    for (int r = 0; r < 4; ++r)
                        o[nf][r] *= alpha;
            }
            const float mc = mrow * SC;

            // exp + pack to bf16 (row-sum comes from ones-MFMA below)
            u32 w0[4], w1[4];
#pragma unroll
            for (int f = 0; f < 4; ++f) {
                float p0 = exp2f(__builtin_fmaf(s[f][0], SC, -mc));
                float p1 = exp2f(__builtin_fmaf(s[f][1], SC, -mc));
                float p2 = exp2f(__builtin_fmaf(s[f][2], SC, -mc));
                float p3 = exp2f(__builtin_fmaf(s[f][3], SC, -mc));
                w0[f] = cvt_pk_bf16(p0, p1);
                w1[f] = cvt_pk_bf16(p2, p3);
            }

            // O^T += mfma(A=V^T-frag, B=P-frag);  os += mfma(ones, P-frag)
            __builtin_amdgcn_s_setprio(1);
#pragma unroll
            for (int ks = 0; ks < 2; ++ks) {
                u32 t00 = (u32)__shfl((int)w0[2 * ks], srcA);
                u32 t01 = (u32)__shfl((int)w0[2 * ks + 1], srcA);
                u32 t10 = (u32)__shfl((int)w1[2 * ks], srcA);
                u32 t11 = (u32)__shfl((int)w1[2 * ks + 1], srcA);
                u32 t20 = (u32)__shfl((int)w0[2 * ks], srcB);
                u32 t21 = (u32)__shfl((int)w0[2 * ks + 1], srcB);
                u32 t30 = (u32)__shfl((int)w1[2 * ks], srcB);
                u32 t31 = (u32)__shfl((int)w1[2 * ks + 1], srcB);
                u32x4 bb;
                bb.x = losel ? t00 : t01;
                bb.y = losel ? t10 : t11;
                bb.z = losel ? t20 : t21;
                bb.w = losel ? t30 : t31;
                bf16x8 pb = __builtin_bit_cast(bf16x8, bb);
                os = __builtin_amdgcn_mfma_f32_16x16x32_bf16(onesA, pb, os, 0, 0, 0);
#pragma unroll
                for (int nf = 0; nf < 4; ++nf) {
                    bf16x8 bv = *reinterpret_cast<const bf16x8*>(
                        Vc + (nf * 16 + l15) * 64 + (((ks * 4 + g) ^ (l15 & 7)) * 8));
                    o[nf] = __builtin_amdgcn_mfma_f32_16x16x32_bf16(bv, pb, o[nf], 0, 0, 0);
                }
            }
            __builtin_amdgcn_s_setprio(0);
            __syncthreads();  // drains vmcnt (prefetch) + protects buffer reuse
            cur ^= 1;
        }
    }

    // partial epilogue: UNNORMALIZED o (bf16) + m, l (f32)
    const float lsum = os[0];
    const size_t oHalf = (size_t)32 * TSEQ * HD;
    u16* oRow = oPart + half * oHalf + ((size_t)bh * TSEQ + qrow) * HD;
#pragma unroll
    for (int nf = 0; nf < 4; ++nf) {
        int d0 = nf * 16 + g * 4;
        u32 p01 = cvt_pk_bf16(o[nf][0], o[nf][1]);
        u32 p23 = cvt_pk_bf16(o[nf][2], o[nf][3]);
        *reinterpret_cast<u32*>(oRow + d0) = p01;
        *reinterpret_cast<u32*>(oRow + d0 + 2) = p23;
    }
    if (g == 0) {
        float* mlH = mlPart + half * ((size_t)32 * 2 * TSEQ);
        mlH[((size_t)bh * 2 + 0) * TSEQ + qrow] = mrow;
        mlH[((size_t)bh * 2 + 1) * TSEQ + qrow] = lsum;
    }
}

// ---------- merge the two K-half partials -> attn [B*T][NE] bf16 ----------
__global__ void k_merge(const u16* __restrict__ oPart, const float* __restrict__ mlPart,
                        u16* __restrict__ attn_out) {
    const float SC = 0.125f * 1.44269504f;
    int tid = blockIdx.x * blockDim.x + threadIdx.x;  // 32*2048*8
    int dblk = tid & 7;
    int q = (tid >> 3) & 2047;
    int bh = tid >> 14;
    const size_t oHalf = (size_t)32 * TSEQ * HD;
    const size_t mlHalf = (size_t)32 * 2 * TSEQ;
    float mA = mlPart[((size_t)bh * 2 + 0) * TSEQ + q];
    float lA = mlPart[((size_t)bh * 2 + 1) * TSEQ + q];
    float mB = mlPart[mlHalf + ((size_t)bh * 2 + 0) * TSEQ + q];
    float lB = mlPart[mlHalf + ((size_t)bh * 2 + 1) * TSEQ + q];
    float M = fmaxf(mA, mB);
    float eA = exp2f((mA - M) * SC);
    float eB = exp2f((mB - M) * SC);
    float invL = 1.0f / (lA * eA + lB * eB);
    float fA = eA * invL, fB = eB * invL;
    const u32* pa = (const u32*)(oPart + ((size_t)bh * TSEQ + q) * HD + dblk * 8);
    const u32* pb = (const u32*)(oPart + oHalf + ((size_t)bh * TSEQ + q) * HD + dblk * 8);
    u32 outw[4];
#pragma unroll
    for (int i = 0; i < 4; ++i) {
        u32 a = pa[i], b = pb[i];
        float lo = bf2f(a & 0xffffu) * fA + bf2f(b & 0xffffu) * fB;
        float hi = bf2f(a >> 16) * fA + bf2f(b >> 16) * fB;
        outw[i] = cvt_pk_bf16(lo, hi);
    }
    int bb = bh >> 4, h = bh & 15;
    u16* dst = attn_out + ((size_t)(bb * TSEQ + q) * NE) + h * HD + dblk * 8;
    *reinterpret_cast<u32x4*>(dst) = *reinterpret_cast<const u32x4*>(outw);
}

extern "C" void kernel_launch(void* const* d_in, const int* in_sizes, int n_in,
                              void* d_out, int out_size, void* d_ws, size_t ws_size,
                              hipStream_t stream) {
    const float* x = (const float*)d_in[0];
    const float* W_attn = (const float*)d_in[1];
    const float* b_attn = (const float*)d_in[2];
    const float* W_proj = (const float*)d_in[3];
    const float* b_proj = (const float*)d_in[4];
    float* out = (float*)d_out;

    char* ws = (char*)d_ws;
    // layout (52MB total):
    //  0..8    xb   [4096,1024] bf16   (dead after QKV GEMM -> reused as oPart half A)
    //  8..14   WaT  [3072,1024] bf16   (dead after QKV GEMM -> reused as oPart half B)
    //  16..40  qkvb q,k [B,H,T,D], v [B,H,D,T] bf16
    //  40..48  attn [4096,1024] bf16
    //  48..50  WpT  [1024,1024] bf16
    //  50..52  mlPart [2][32][2][2048] f32
    u16* xb     = (u16*)(ws);
    u16* WaT    = (u16*)(ws + 8 * MB);
    u16* qkvb   = (u16*)(ws + 16 * MB);
    u16* attn   = (u16*)(ws + 40 * MB);
    u16* WpT    = (u16*)(ws + 48 * MB);
    float* mlP  = (float*)(ws + 50 * MB);
    u16* oPart  = (u16*)(ws);  // half A at 0..8MB, half B at 8..16MB

    const int M = BATCH * TSEQ;  // 4096

    k_f32_to_bf16<<<2048, 256, 0, stream>>>(x, xb, (M * NE) / 4);
    k_prep_w<<<dim3(128, NE / 32), dim3(32, 8), 0, stream>>>(W_attn, W_proj, WaT, WpT);

    k_gemm_bt<0><<<dim3(M / 128, (3 * NE) / 128), 256, 0, stream>>>(xb, WaT, b_attn, qkvb, M, 3 * NE, NE);

    const size_t headsz = (size_t)BATCH * NH * TSEQ * HD;  // 4M elems
    k_attn<<<dim3(32 * 2 * 32), 256, 0, stream>>>(qkvb, qkvb + headsz, qkvb + 2 * headsz, oPart, mlP);

    k_merge<<<dim3((32 * TSEQ * 8) / 256), 256, 0, stream>>>(oPart, mlP, attn);

    k_gemm_bt<1><<<dim3(M / 128, NE / 128), 256, 0, stream>>>(attn, WpT, b_proj, out, M, NE, NE);
}

// Round 11
// 124.914 us; speedup vs baseline: 1.0788x; 1.0028x over previous
//
#include <hip/hip_runtime.h>
#include <hip/hip_bf16.h>

#define NE 1024       // N_EMBD
#define NH 16         // N_HEAD
#define HD 64         // HEAD_SIZE
#define TSEQ 2048
#define BATCH 2
#define MB (1024u * 1024u)

typedef __attribute__((ext_vector_type(8))) short bf16x8;
typedef __attribute__((ext_vector_type(4))) float f32x4;
typedef __attribute__((ext_vector_type(4))) unsigned int u32x4;
typedef unsigned short u16;
typedef unsigned int u32;

__device__ inline u16 f2bf(float f) {
    __hip_bfloat16 h = __float2bfloat16(f);
    return *reinterpret_cast<u16*>(&h);
}

__device__ inline float bf2f(u32 bits) {
    u32 v = bits << 16;
    return __builtin_bit_cast(float, v);
}

__device__ inline u32 cvt_pk_bf16(float lo, float hi) {
    u32 r;
    asm("v_cvt_pk_bf16_f32 %0, %1, %2" : "=v"(r) : "v"(lo), "v"(hi));
    return r;
}

#define GLD16(gptr, lptr)                                                        \
    __builtin_amdgcn_global_load_lds(                                            \
        (const __attribute__((address_space(1))) void*)(gptr),                   \
        (__attribute__((address_space(3))) void*)(lptr), 16, 0, 0)

// ---------- elementwise f32 -> bf16 ----------
__global__ void k_f32_to_bf16(const float* __restrict__ in, u16* __restrict__ out, int n4) {
    int i = blockIdx.x * blockDim.x + threadIdx.x;
    int stride = gridDim.x * blockDim.x;
    for (; i < n4; i += stride) {
        float4 v = reinterpret_cast<const float4*>(in)[i];
        ushort4 o;
        o.x = f2bf(v.x); o.y = f2bf(v.y); o.z = f2bf(v.z); o.w = f2bf(v.w);
        reinterpret_cast<ushort4*>(out)[i] = o;
    }
}

// ---------- combined transpose+convert for BOTH weights ----------
__global__ void k_prep_w(const float* __restrict__ Wa, const float* __restrict__ Wp,
                         u16* __restrict__ WaT, u16* __restrict__ WpT) {
    __shared__ float tile[32][33];
    const bool isA = blockIdx.x < 96;
    const float* in = isA ? Wa : Wp;
    u16* out = isA ? WaT : WpT;
    const int N = isA ? 3 * NE : NE;
    const int K = NE;
    int bn = (isA ? blockIdx.x : blockIdx.x - 96) * 32;
    int bk = blockIdx.y * 32;
    int tx = threadIdx.x, ty = threadIdx.y;
#pragma unroll
    for (int i = 0; i < 32; i += 8)
        tile[ty + i][tx] = in[(size_t)(bk + ty + i) * N + bn + tx];
    __syncthreads();
#pragma unroll
    for (int i = 0; i < 32; i += 8)
        out[(size_t)(bn + ty + i) * K + bk + tx] = f2bf(tile[tx][ty + i]);
}

// ---------- GEMM: C[M,N] = A[M,K] * Bt[N,K]^T + bias ----------
// Double-buffered LDS; prefetch kt+1 before computing kt, 1 barrier per K-step.
// MODE 0: scatter q/k -> [B,H,T,D] bf16, v -> [B,H,D,T] bf16 (transposed)
// MODE 1: plain f32 out
template <int MODE>
__global__ __launch_bounds__(256, 2) void k_gemm_bt(
    const u16* __restrict__ A, const u16* __restrict__ Bt,
    const float* __restrict__ bias, void* __restrict__ outp,
    int M, int N, int K) {
    __shared__ __align__(16) u16 As[2][128 * 32];
    __shared__ __align__(16) u16 Bs[2][128 * 32];
    const int l = threadIdx.x & 63;
    const int w = threadIdx.x >> 6;
    const int m0 = blockIdx.x * 128;
    const int n0 = blockIdx.y * 128;
    const int wr = w >> 1, wc = w & 1;
    const int srow = l >> 2;
    const int scol = (l & 3) * 8;

    f32x4 acc[4][4] = {};
    const int nkt = K >> 5;

#pragma unroll
    for (int i = 0; i < 2; ++i) {
        int c = w * 2 + i;
        GLD16(A + (size_t)(m0 + c * 16 + srow) * K + scol, &As[0][c * 512]);
        GLD16(Bt + (size_t)(n0 + c * 16 + srow) * K + scol, &Bs[0][c * 512]);
    }
    __syncthreads();

    int cur = 0;
    for (int kt = 0; kt < nkt; ++kt) {
        if (kt + 1 < nkt) {
            int nb = cur ^ 1;
            int kc = ((kt + 1) << 5) + scol;
#pragma unroll
            for (int i = 0; i < 2; ++i) {
                int c = w * 2 + i;
                GLD16(A + (size_t)(m0 + c * 16 + srow) * K + kc, &As[nb][c * 512]);
                GLD16(Bt + (size_t)(n0 + c * 16 + srow) * K + kc, &Bs[nb][c * 512]);
            }
        }
        bf16x8 af[4], bfr[4];
#pragma unroll
        for (int mi = 0; mi < 4; ++mi)
            af[mi] = *reinterpret_cast<const bf16x8*>(
                &As[cur][(wr * 64 + mi * 16 + (l & 15)) * 32 + (l >> 4) * 8]);
#pragma unroll
        for (int ni = 0; ni < 4; ++ni)
            bfr[ni] = *reinterpret_cast<const bf16x8*>(
                &Bs[cur][(wc * 64 + ni * 16 + (l & 15)) * 32 + (l >> 4) * 8]);
#pragma unroll
        for (int mi = 0; mi < 4; ++mi)
#pragma unroll
            for (int ni = 0; ni < 4; ++ni)
                acc[mi][ni] = __builtin_amdgcn_mfma_f32_16x16x32_bf16(af[mi], bfr[ni], acc[mi][ni], 0, 0, 0);
        __syncthreads();
        cur ^= 1;
    }

    if (MODE == 1) {
        float* C = (float*)outp;
#pragma unroll
        for (int mi = 0; mi < 4; ++mi)
#pragma unroll
            for (int ni = 0; ni < 4; ++ni) {
                int n = n0 + wc * 64 + ni * 16 + (l & 15);
                float bv = bias[n];
#pragma unroll
                for (int r = 0; r < 4; ++r) {
                    int m = m0 + wr * 64 + mi * 16 + (l >> 4) * 4 + r;
                    C[(size_t)m * N + n] = acc[mi][ni][r] + bv;
                }
            }
    } else {
        u16* qkv = (u16*)outp;
        const size_t headsz = (size_t)BATCH * NH * TSEQ * HD;
#pragma unroll
        for (int mi = 0; mi < 4; ++mi)
#pragma unroll
            for (int ni = 0; ni < 4; ++ni) {
                int n = n0 + wc * 64 + ni * 16 + (l & 15);
                float bv = bias[n];
                int which = n >> 10;
                int c = n & 1023;
                int h = c >> 6, d = c & 63;
#pragma unroll
                for (int r = 0; r < 4; ++r) {
                    int m = m0 + wr * 64 + mi * 16 + (l >> 4) * 4 + r;
                    int b = m >> 11, t = m & 2047;
                    float v = acc[mi][ni][r] + bv;
                    size_t dst;
                    if (which == 2)  // V stored transposed: [B,H,D,T]
                        dst = 2 * headsz + ((size_t)(b * NH + h) * HD + d) * TSEQ + t;
                    else
                        dst = (size_t)which * headsz + ((size_t)(b * NH + h) * TSEQ + t) * HD + d;
                    qkv[dst] = f2bf(v);
                }
            }
    }
}

// ---------- causal flash attention: QBLK=128 (2 q-frags/wave), K-split x2 ----------
// grid: 1024 blocks = 16 q-tiles x 2 k-halves x 32 bh, 4 waves, 32KB LDS.
// Wave w owns rows [w*32, w*32+32) as two 16-row fragments (qn=0,1); the K/V
// LDS fragments are read ONCE and feed both qn MFMAs (halves LDS-pipe cost/row).
// m initialized to 0 (NOT -1e30): online softmax only needs m finite &
// non-decreasing; this makes fully-masked rows give pe=exp2(-1e30*SC-0)=0
// exactly (the -1e30 init had a fma-ulp hazard: exp2(+2e22)=inf -> NaN).
// Writes UNNORMALIZED partials (o bf16, m/l f32); k_merge combines.
__global__ __launch_bounds__(256, 4) void k_attn(
    const u16* __restrict__ qb, const u16* __restrict__ kb, const u16* __restrict__ vtb,
    u16* __restrict__ oPart, float* __restrict__ mlPart) {
    __shared__ __align__(16) u16 Ks[2][64 * 64];
    __shared__ __align__(16) u16 Vs[2][64 * 64];
    const int l = threadIdx.x & 63;
    const int w = threadIdx.x >> 6;
    const int g = l >> 4, l15 = l & 15;

    const int bid = blockIdx.x;
    const int t = 15 - (bid >> 6);        // 128-row q-tile, heavy first
    const int half = (bid >> 5) & 1;
    const int bh = bid & 31;
    const int q0 = t * 128;
    const int ktLo = half ? (t + 1) : 0;
    const int ktHi = half ? (2 * t + 2) : (t + 1);

    const size_t base = (size_t)bh * TSEQ * HD;
    const u16* Q = qb + base;
    const u16* Kg = kb + base;
    const u16* Vg = vtb + base;  // [64 d][2048 t]

    const int lrow8 = l >> 3;
    const int lchunk = (l & 7) ^ lrow8;  // inverse-swizzled source chunk

    const int qrow0 = q0 + w * 32 + l15;
    const int qrow1 = qrow0 + 16;
    bf16x8 qa[2][2];  // [qn][ks]
#pragma unroll
    for (int ks = 0; ks < 2; ++ks) {
        qa[0][ks] = *reinterpret_cast<const bf16x8*>(Q + (size_t)qrow0 * HD + ks * 32 + g * 8);
        qa[1][ks] = *reinterpret_cast<const bf16x8*>(Q + (size_t)qrow1 * HD + ks * 32 + g * 8);
    }

    float m[2] = {0.f, 0.f};       // SAFE init (see header comment)
    f32x4 o[2][4] = {};            // [qn][nf]
    f32x4 os[2] = {};              // ones-MFMA row-sum accumulators

    const float SC = 0.125f * 1.44269504f;  // log2(e)/sqrt(64)
    const float THRU = 44.3614f;            // 8/SC

    const int srcA = ((2 * g) & 3) * 16 + l15;
    const int srcB = ((2 * g + 1) & 3) * 16 + l15;
    const bool losel = (g < 2);

    u32x4 onesw = {0x3F803F80u, 0x3F803F80u, 0x3F803F80u, 0x3F803F80u};
    const bf16x8 onesA = __builtin_bit_cast(bf16x8, onesw);

    // prologue: stage tile ktLo into buffer 0
#pragma unroll
    for (int i2 = 0; i2 < 2; ++i2) {
        int c = w * 2 + i2;
        GLD16(Kg + (size_t)(ktLo * 64 + c * 8 + lrow8) * HD + lchunk * 8, &Ks[0][c * 512]);
        GLD16(Vg + (size_t)(c * 8 + lrow8) * TSEQ + ktLo * 64 + lchunk * 8, &Vs[0][c * 512]);
    }
    __syncthreads();

    int cur = 0;
    for (int kt = ktLo; kt < ktHi; ++kt) {
        if (kt + 1 < ktHi) {
            int nb = cur ^ 1;
#pragma unroll
            for (int i2 = 0; i2 < 2; ++i2) {
                int c = w * 2 + i2;
                GLD16(Kg + (size_t)((kt + 1) * 64 + c * 8 + lrow8) * HD + lchunk * 8,
                      &Ks[nb][c * 512]);
                GLD16(Vg + (size_t)(c * 8 + lrow8) * TSEQ + (kt + 1) * 64 + lchunk * 8,
                      &Vs[nb][c * 512]);
            }
        }
        const u16* Kc = Ks[cur];
        const u16* Vc = Vs[cur];

        // S^T: s[f][qn][r] = S[q][k=kt*64+f*16+g*4+r]; K-frag shared by both qn
        f32x4 s[4][2] = {};
        __builtin_amdgcn_s_setprio(1);
#pragma unroll
        for (int f = 0; f < 4; ++f)
#pragma unroll
            for (int ks = 0; ks < 2; ++ks) {
                bf16x8 bk = *reinterpret_cast<const bf16x8*>(
                    Kc + (f * 16 + l15) * 64 + (((ks * 4 + g) ^ (l15 & 7)) * 8));
                s[f][0] = __builtin_amdgcn_mfma_f32_16x16x32_bf16(bk, qa[0][ks], s[f][0], 0, 0, 0);
                s[f][1] = __builtin_amdgcn_mfma_f32_16x16x32_bf16(bk, qa[1][ks], s[f][1], 0, 0, 0);
            }
        __builtin_amdgcn_s_setprio(0);

        // causal mask on tiles crossing the diagonal band (kt >= 2t)
        if (kt >= 2 * t) {
#pragma unroll
            for (int f = 0; f < 4; ++f)
#pragma unroll
                for (int r = 0; r < 4; ++r) {
                    int kg = (kt << 6) + f * 16 + g * 4 + r;
                    if (kg > qrow0) s[f][0][r] = -1e30f;
                    if (kg > qrow1) s[f][1][r] = -1e30f;
                }
        }

        // per-qn lane-local online softmax + bf16 pack
        u32 pk0[2][4], pk1[2][4];
#pragma unroll
        for (int qn = 0; qn < 2; ++qn) {
            float rmax = -1e30f;
#pragma unroll
            for (int f = 0; f < 4; ++f)
                rmax = fmaxf(rmax, fmaxf(fmaxf(s[f][qn][0], s[f][qn][1]),
                                         fmaxf(s[f][qn][2], s[f][qn][3])));
            rmax = fmaxf(rmax, __shfl_xor(rmax, 16));
            rmax = fmaxf(rmax, __shfl_xor(rmax, 32));

            if (__any(rmax - m[qn] > THRU)) {
                float mnew = fmaxf(m[qn], rmax);
                float alpha = exp2f((m[qn] - mnew) * SC);
                m[qn] = mnew;
#pragma unroll
                for (int r = 0; r < 4; ++r)
                    os[qn][r] *= alpha;
#pragma unroll
                for (int nf = 0; nf < 4; ++nf)
#pragma unroll
                    for (int r = 0; r < 4; ++r)
                        o[qn][nf][r] *= alpha;
            }
            const float mc = m[qn] * SC;
#pragma unroll
            for (int f = 0; f < 4; ++f) {
                float p0 = exp2f(__builtin_fmaf(s[f][qn][0], SC, -mc));
                float p1 = exp2f(__builtin_fmaf(s[f][qn][1], SC, -mc));
                float p2 = exp2f(__builtin_fmaf(s[f][qn][2], SC, -mc));
                float p3 = exp2f(__builtin_fmaf(s[f][qn][3], SC, -mc));
                pk0[qn][f] = cvt_pk_bf16(p0, p1);
                pk1[qn][f] = cvt_pk_bf16(p2, p3);
            }
        }

        // O^T += mfma(V^T-frag, P-frag); V-frag shared by both qn
        __builtin_amdgcn_s_setprio(1);
#pragma unroll
        for (int ks = 0; ks < 2; ++ks) {
            bf16x8 pb[2];
#pragma unroll
            for (int qn = 0; qn < 2; ++qn) {
                u32 t00 = (u32)__shfl((int)pk0[qn][2 * ks], srcA);
                u32 t01 = (u32)__shfl((int)pk0[qn][2 * ks + 1], srcA);
                u32 t10 = (u32)__shfl((int)pk1[qn][2 * ks], srcA);
                u32 t11 = (u32)__shfl((int)pk1[qn][2 * ks + 1], srcA);
                u32 t20 = (u32)__shfl((int)pk0[qn][2 * ks], srcB);
                u32 t21 = (u32)__shfl((int)pk0[qn][2 * ks + 1], srcB);
                u32 t30 = (u32)__shfl((int)pk1[qn][2 * ks], srcB);
                u32 t31 = (u32)__shfl((int)pk1[qn][2 * ks + 1], srcB);
                u32x4 bb;
                bb.x = losel ? t00 : t01;
                bb.y = losel ? t10 : t11;
                bb.z = losel ? t20 : t21;
                bb.w = losel ? t30 : t31;
                pb[qn] = __builtin_bit_cast(bf16x8, bb);
            }
            os[0] = __builtin_amdgcn_mfma_f32_16x16x32_bf16(onesA, pb[0], os[0], 0, 0, 0);
            os[1] = __builtin_amdgcn_mfma_f32_16x16x32_bf16(onesA, pb[1], os[1], 0, 0, 0);
#pragma unroll
            for (int nf = 0; nf < 4; ++nf) {
                bf16x8 bv = *reinterpret_cast<const bf16x8*>(
                    Vc + (nf * 16 + l15) * 64 + (((ks * 4 + g) ^ (l15 & 7)) * 8));
                o[0][nf] = __builtin_amdgcn_mfma_f32_16x16x32_bf16(bv, pb[0], o[0][nf], 0, 0, 0);
                o[1][nf] = __builtin_amdgcn_mfma_f32_16x16x32_bf16(bv, pb[1], o[1][nf], 0, 0, 0);
            }
        }
        __builtin_amdgcn_s_setprio(0);
        __syncthreads();
        cur ^= 1;
    }

    // partial epilogue: UNNORMALIZED o (bf16) + m, l (f32)
    const size_t oHalf = (size_t)32 * TSEQ * HD;
#pragma unroll
    for (int qn = 0; qn < 2; ++qn) {
        int qrow = qn ? qrow1 : qrow0;
        u16* oRow = oPart + half * oHalf + ((size_t)bh * TSEQ + qrow) * HD;
#pragma unroll
        for (int nf = 0; nf < 4; ++nf) {
            int d0 = nf * 16 + g * 4;
            u32 p01 = cvt_pk_bf16(o[qn][nf][0], o[qn][nf][1]);
            u32 p23 = cvt_pk_bf16(o[qn][nf][2], o[qn][nf][3]);
            *reinterpret_cast<u32*>(oRow + d0) = p01;
            *reinterpret_cast<u32*>(oRow + d0 + 2) = p23;
        }
        if (g == 0) {
            float* mlH = mlPart + half * ((size_t)32 * 2 * TSEQ);
            mlH[((size_t)bh * 2 + 0) * TSEQ + qrow] = m[qn];
            mlH[((size_t)bh * 2 + 1) * TSEQ + qrow] = os[qn][0];
        }
    }
}

// ---------- merge the two K-half partials -> attn [B*T][NE] bf16 ----------
__global__ void k_merge(const u16* __restrict__ oPart, const float* __restrict__ mlPart,
                        u16* __restrict__ attn_out) {
    const float SC = 0.125f * 1.44269504f;
    int tid = blockIdx.x * blockDim.x + threadIdx.x;  // 32*2048*8
    int dblk = tid & 7;
    int q = (tid >> 3) & 2047;
    int bh = tid >> 14;
    const size_t oHalf = (size_t)32 * TSEQ * HD;
    const size_t mlHalf = (size_t)32 * 2 * TSEQ;
    float mA = mlPart[((size_t)bh * 2 + 0) * TSEQ + q];
    float lA = mlPart[((size_t)bh * 2 + 1) * TSEQ + q];
    float mB = mlPart[mlHalf + ((size_t)bh * 2 + 0) * TSEQ + q];
    float lB = mlPart[mlHalf + ((size_t)bh * 2 + 1) * TSEQ + q];
    float M = fmaxf(mA, mB);
    float eA = exp2f((mA - M) * SC);
    float eB = exp2f((mB - M) * SC);
    float invL = 1.0f / (lA * eA + lB * eB);
    float fA = eA * invL, fB = eB * invL;
    const u32* pa = (const u32*)(oPart + ((size_t)bh * TSEQ + q) * HD + dblk * 8);
    const u32* pb = (const u32*)(oPart + oHalf + ((size_t)bh * TSEQ + q) * HD + dblk * 8);
    u32 outw[4];
#pragma unroll
    for (int i = 0; i < 4; ++i) {
        u32 a = pa[i], b = pb[i];
        float lo = bf2f(a & 0xffffu) * fA + bf2f(b & 0xffffu) * fB;
        float hi = bf2f(a >> 16) * fA + bf2f(b >> 16) * fB;
        outw[i] = cvt_pk_bf16(lo, hi);
    }
    int bb = bh >> 4, h = bh & 15;
    u16* dst = attn_out + ((size_t)(bb * TSEQ + q) * NE) + h * HD + dblk * 8;
    *reinterpret_cast<u32x4*>(dst) = *reinterpret_cast<const u32x4*>(outw);
}

extern "C" void kernel_launch(void* const* d_in, const int* in_sizes, int n_in,
                              void* d_out, int out_size, void* d_ws, size_t ws_size,
                              hipStream_t stream) {
    const float* x = (const float*)d_in[0];
    const float* W_attn = (const float*)d_in[1];
    const float* b_attn = (const float*)d_in[2];
    const float* W_proj = (const float*)d_in[3];
    const float* b_proj = (const float*)d_in[4];
    float* out = (float*)d_out;

    char* ws = (char*)d_ws;
    // layout (43MB peak):
    //  0..8    xb   [4096,1024] bf16  (dead after QKV GEMM -> oPart half A)
    //  8..14   WaT  [3072,1024] bf16  (dead after QKV GEMM -> oPart half B 8..16)
    //  16..40  qkvb q,k [B,H,T,D], v [B,H,D,T]  (q region 16..24 -> attn out)
    //  40..42  WpT  [1024,1024] bf16  (live until proj GEMM)
    //  42..43  mlPart [2][32][2][2048] f32
    u16* xb     = (u16*)(ws);
    u16* WaT    = (u16*)(ws + 8 * MB);
    u16* qkvb   = (u16*)(ws + 16 * MB);
    u16* WpT    = (u16*)(ws + 40 * MB);
    float* mlP  = (float*)(ws + 42 * MB);
    u16* oPart  = (u16*)(ws);             // halves at 0..8 and 8..16
    u16* attn   = (u16*)(ws + 16 * MB);   // overwrites dead q

    const int M = BATCH * TSEQ;  // 4096

    k_f32_to_bf16<<<2048, 256, 0, stream>>>(x, xb, (M * NE) / 4);
    k_prep_w<<<dim3(128, NE / 32), dim3(32, 8), 0, stream>>>(W_attn, W_proj, WaT, WpT);

    k_gemm_bt<0><<<dim3(M / 128, (3 * NE) / 128), 256, 0, stream>>>(xb, WaT, b_attn, qkvb, M, 3 * NE, NE);

    const size_t headsz = (size_t)BATCH * NH * TSEQ * HD;  // 4M elems
    k_attn<<<dim3(16 * 2 * 32), 256, 0, stream>>>(qkvb, qkvb + headsz, qkvb + 2 * headsz, oPart, mlP);

    k_merge<<<dim3((32 * TSEQ * 8) / 256), 256, 0, stream>>>(oPart, mlP, attn);

    k_gemm_bt<1><<<dim3(M / 128, NE / 128), 256, 0, stream>>>(attn, WpT, b_proj, out, M, NE, NE);
}